// Round 7
// baseline (208.089 us; speedup 1.0000x reference)
//
#include <hip/hip_runtime.h>
#include <climits>

#define B_ 2
#define N_ 512
#define C_ 128
#define H_ 128
#define W_ 128
#define HW_ (H_ * W_)
#define NUM_NEG_ 16
#define SOS_NEG_ 8
#define SCAP_ 128   // survivor cap per row

typedef __attribute__((ext_vector_type(8))) short short8;
typedef __attribute__((ext_vector_type(4))) float f32x4;

__device__ inline unsigned int f2bf(float x) {
    unsigned int u = __float_as_uint(x);
    return (u + 0x7FFFu + ((u >> 16) & 1u)) >> 16;
}
__device__ inline float bf2f(unsigned int h) {
    return __uint_as_float(h << 16);
}

// ---------------------------------------------------------------------------
// 4 nearest grid-cell centers of point (y,x); tie-break matches lax.top_k.
// ---------------------------------------------------------------------------
__device__ inline void nearest4(float y, float x, int out[4]) {
    y = fminf(fmaxf(y, -1e6f), 1e6f);
    x = fminf(fmaxf(x, -1e6f), 1e6f);
    int fy = (int)floorf(y * 0.125f - 0.5f);
    int fx = (int)floorf(x * 0.125f - 0.5f);
    int ylo = fy - 1; if (ylo < 0) ylo = 0; if (ylo > H_ - 4) ylo = H_ - 4;
    int xlo = fx - 1; if (xlo < 0) xlo = 0; if (xlo > W_ - 4) xlo = W_ - 4;
    float bd[4] = {1e30f, 1e30f, 1e30f, 1e30f};
    int   bi[4] = {INT_MAX, INT_MAX, INT_MAX, INT_MAX};
#pragma unroll
    for (int dyi = 0; dyi < 4; ++dyi) {
        int yi = ylo + dyi;
        float dy = y - (8.0f * yi + 4.0f);
        float dy2 = dy * dy;
#pragma unroll
        for (int dxi = 0; dxi < 4; ++dxi) {
            int xi = xlo + dxi;
            float dx = x - (8.0f * xi + 4.0f);
            float d = dy2 + dx * dx;
            int id = yi * W_ + xi;
#pragma unroll
            for (int k = 0; k < 4; ++k) {
                bool sm = (d < bd[k]) || (d == bd[k] && id < bi[k]);
                float od = bd[k]; int oi = bi[k];
                bd[k] = sm ? d : od;  bi[k] = sm ? id : oi;
                d = sm ? od : d;      id = sm ? oi : id;
            }
        }
    }
    out[0] = bi[0]; out[1] = bi[1]; out[2] = bi[2]; out[3] = bi[3];
}

__device__ inline void k1_body(int t, const float* kp1, const float* w_kp1,
                               const float* homo, int* cid4, int* wcc16,
                               int* wid4, unsigned int* marked) {
    int b = t / N_;
    float ky = kp1[2 * t], kx = kp1[2 * t + 1];
    int ids[4];
    nearest4(ky, kx, ids);
    const float* Hb = homo + 9 * b;
    float h00 = Hb[0], h01 = Hb[1], h02 = Hb[2];
    float h10 = Hb[3], h11 = Hb[4], h12 = Hb[5];
    float h20 = Hb[6], h21 = Hb[7], h22 = Hb[8];
    int w16[16];
#pragma unroll
    for (int i = 0; i < 4; ++i) {
        int id = ids[i];
        cid4[4 * t + i] = id;
        float cy = 8.0f * (id >> 7) + 4.0f;
        float cx = 8.0f * (id & 127) + 4.0f;
        float X = cx, Y = cy;
        float wz = h20 * X + h21 * Y + h22;
        float inv = 1.0f / (wz + 1e-8f);
        float wy = (h10 * X + h11 * Y + h12) * inv;
        float wx = (h00 * X + h01 * Y + h02) * inv;
        int wids[4];
        nearest4(wy, wx, wids);
#pragma unroll
        for (int j = 0; j < 4; ++j) {
            w16[4 * i + j] = wids[j];
            wcc16[16 * t + 4 * i + j] = wids[j];
        }
    }
#pragma unroll
    for (int i = 0; i < 16; ++i) {
        int cnt = 0; bool first = true;
#pragma unroll
        for (int j = 0; j < 16; ++j) {
            bool eq = (w16[j] == w16[i]);
            cnt += eq ? 1 : 0;
            if (j < i && eq) first = false;
        }
        marked[16 * t + i] = first ? ((unsigned int)w16[i] | ((unsigned int)cnt << 16))
                                   : 0xFFFFFFFFu;
    }
    float zy = w_kp1[2 * t], zx = w_kp1[2 * t + 1];
    int wi4[4];
    nearest4(zy, zx, wi4);
#pragma unroll
    for (int j = 0; j < 4; ++j) wid4[4 * t + j] = wi4[j];
}

// ---------------------------------------------------------------------------
// KA fused: [0,1024) d2t transpose; [1024,1152) q_bf; 1152 zero scnt/acc;
// [1153,1157) k1; [1157,1413) k2 (wave-per-keypoint, shfl-only).
// ---------------------------------------------------------------------------
__global__ __launch_bounds__(256) void hqt_ka(
    const float* __restrict__ desc2, const float* __restrict__ kp1_desc,
    const float* __restrict__ kp1, const float* __restrict__ w_kp1,
    const float* __restrict__ homo,
    unsigned short* __restrict__ d2t, unsigned short* __restrict__ q_bf,
    unsigned short* __restrict__ w_bf, float* __restrict__ pos,
    int* __restrict__ cid4, int* __restrict__ wcc16, int* __restrict__ wid4,
    unsigned int* __restrict__ marked, int* __restrict__ scnt,
    float* __restrict__ acc) {
    int blk = blockIdx.x;
    int tid = threadIdx.x;
    if (blk < 1024) {
        __shared__ float tile[32][129];
        int b = blk >> 9;
        int j0 = (blk & 511) * 32;
        int jj = tid & 31, cg = tid >> 5;
        const float* src = desc2 + (size_t)b * C_ * HW_;
#pragma unroll
        for (int cc = 0; cc < 16; ++cc) {
            int c = cg * 16 + cc;
            tile[jj][c] = src[(size_t)c * HW_ + j0 + jj];
        }
        __syncthreads();
        int row = tid >> 3, c8 = (tid & 7) * 16;
        unsigned int tmp[16];
#pragma unroll
        for (int k = 0; k < 16; ++k) tmp[k] = f2bf(tile[row][c8 + k]);
        uint4 o0, o1;
        o0.x = tmp[0] | (tmp[1] << 16);  o0.y = tmp[2] | (tmp[3] << 16);
        o0.z = tmp[4] | (tmp[5] << 16);  o0.w = tmp[6] | (tmp[7] << 16);
        o1.x = tmp[8] | (tmp[9] << 16);  o1.y = tmp[10] | (tmp[11] << 16);
        o1.z = tmp[12] | (tmp[13] << 16); o1.w = tmp[14] | (tmp[15] << 16);
        unsigned short* dst = d2t + ((size_t)(b << 14) + j0 + row) * C_ + c8;
        ((uint4*)dst)[0] = o0;
        ((uint4*)dst)[1] = o1;
    } else if (blk < 1152) {
        int idx = (blk - 1024) * 256 + tid;
        float4 v = *(const float4*)(kp1_desc + (size_t)idx * 4);
        uint2 u;
        u.x = f2bf(v.x) | (f2bf(v.y) << 16);
        u.y = f2bf(v.z) | (f2bf(v.w) << 16);
        *(uint2*)(q_bf + (size_t)idx * 4) = u;
    } else if (blk == 1152) {
        ((int4*)scnt)[tid] = make_int4(0, 0, 0, 0);
        if (tid == 0) { acc[0] = 0.0f; acc[1] = 0.0f; acc[2] = 0.0f; acc[3] = 0.0f; }
    } else if (blk < 1157) {
        int t = (blk - 1153) * 256 + tid;
        if (t < B_ * N_)
            k1_body(t, kp1, w_kp1, homo, cid4, wcc16, wid4, marked);
    } else {
        int w = tid >> 6, l = tid & 63;
        int bn = (blk - 1157) * 4 + w;
        int b = bn / N_;
        float ky = w_kp1[2 * bn], kx = w_kp1[2 * bn + 1];
        float y = fminf(fmaxf(ky * 0.125f - 0.5f, 0.0f), (float)(H_ - 1));
        float x = fminf(fmaxf(kx * 0.125f - 0.5f, 0.0f), (float)(W_ - 1));
        int y0 = (int)floorf(y); if (y0 > H_ - 2) y0 = H_ - 2;
        int x0 = (int)floorf(x); if (x0 > W_ - 2) x0 = W_ - 2;
        float wy = y - (float)y0, wx = x - (float)x0;
        int i00 = y0 * W_ + x0;
        float w00 = (1.0f - wy) * (1.0f - wx), w01 = (1.0f - wy) * wx;
        float w10 = wy * (1.0f - wx),          w11 = wy * wx;
        const float* dB0 = desc2 + ((size_t)b * C_ + l) * HW_;
        const float* dB1 = desc2 + ((size_t)b * C_ + l + 64) * HW_;
        float v0 = dB0[i00] * w00 + dB0[i00 + 1] * w01
                 + dB0[i00 + W_] * w10 + dB0[i00 + W_ + 1] * w11;
        float v1 = dB1[i00] * w00 + dB1[i00 + 1] * w01
                 + dB1[i00 + W_] * w10 + dB1[i00 + W_ + 1] * w11;
        float s = v0 * v0 + v1 * v1;
        s += __shfl_xor(s, 1);  s += __shfl_xor(s, 2);  s += __shfl_xor(s, 4);
        s += __shfl_xor(s, 8);  s += __shfl_xor(s, 16); s += __shfl_xor(s, 32);
        float inv = 1.0f / (sqrtf(s) + 1e-8f);
        float vn0 = v0 * inv, vn1 = v1 * inv;
        w_bf[(size_t)bn * C_ + l]      = (unsigned short)f2bf(vn0);
        w_bf[(size_t)bn * C_ + 64 + l] = (unsigned short)f2bf(vn1);
        float qd0 = kp1_desc[(size_t)bn * C_ + l];
        float qd1 = kp1_desc[(size_t)bn * C_ + 64 + l];
        float d = qd0 * vn0 + qd1 * vn1;
        d += __shfl_xor(d, 1);  d += __shfl_xor(d, 2);  d += __shfl_xor(d, 4);
        d += __shfl_xor(d, 8);  d += __shfl_xor(d, 16); d += __shfl_xor(d, 32);
        if (l == 0) pos[bn] = 2.0f - 2.0f * d;
    }
}

// ---------------------------------------------------------------------------
// KB fused: [0,256) k3a rowmax pass; [256,384) k4a psim pass.
// ---------------------------------------------------------------------------
__global__ __launch_bounds__(512) void hqt_kb(
    const unsigned short* __restrict__ q_bf,
    const unsigned short* __restrict__ w_bf,
    const unsigned short* __restrict__ d2t,
    const int* __restrict__ cid4, const int* __restrict__ wid4,
    const int* __restrict__ wcc16,
    float* __restrict__ rowmax, float* __restrict__ psim) {
    int blk = blockIdx.x;
    int tid = threadIdx.x, w = tid >> 6, l = tid & 63;
    int l15 = l & 15, lg = l >> 4;
    if (blk < 256) {
        int b = blk >> 7;
        int rg = (blk >> 4) & 7;
        int cb = blk & 15;
        int rowbase = rg * 64;
        int colbase = cb * 1024 + w * 128;
        const unsigned short* qb = q_bf + (size_t)b * N_ * C_;
        const unsigned short* db = d2t + (size_t)b * HW_ * C_;
        short8 a[4][4];
#pragma unroll
        for (int rt = 0; rt < 4; ++rt)
#pragma unroll
            for (int ks = 0; ks < 4; ++ks)
                a[rt][ks] = *(const short8*)(qb + (size_t)(rowbase + rt * 16 + l15) * C_ + ks * 32 + lg * 8);
        f32x4 mx[4];
#pragma unroll
        for (int rt = 0; rt < 4; ++rt) mx[rt] = f32x4{-1e30f, -1e30f, -1e30f, -1e30f};
#pragma unroll
        for (int t = 0; t < 8; ++t) {
            const unsigned short* dp = db + (size_t)(colbase + t * 16 + l15) * C_ + lg * 8;
            short8 b0 = *(const short8*)(dp);
            short8 b1 = *(const short8*)(dp + 32);
            short8 b2 = *(const short8*)(dp + 64);
            short8 b3 = *(const short8*)(dp + 96);
#pragma unroll
            for (int rt = 0; rt < 4; ++rt) {
                f32x4 acc4 = {0.0f, 0.0f, 0.0f, 0.0f};
                acc4 = __builtin_amdgcn_mfma_f32_16x16x32_bf16(a[rt][0], b0, acc4, 0, 0, 0);
                acc4 = __builtin_amdgcn_mfma_f32_16x16x32_bf16(a[rt][1], b1, acc4, 0, 0, 0);
                acc4 = __builtin_amdgcn_mfma_f32_16x16x32_bf16(a[rt][2], b2, acc4, 0, 0, 0);
                acc4 = __builtin_amdgcn_mfma_f32_16x16x32_bf16(a[rt][3], b3, acc4, 0, 0, 0);
#pragma unroll
                for (int r = 0; r < 4; ++r) mx[rt][r] = fmaxf(mx[rt][r], acc4[r]);
            }
        }
#pragma unroll
        for (int rt = 0; rt < 4; ++rt)
#pragma unroll
            for (int r = 0; r < 4; ++r) {
                float v = mx[rt][r];
                v = fmaxf(v, __shfl_xor(v, 1));
                v = fmaxf(v, __shfl_xor(v, 2));
                v = fmaxf(v, __shfl_xor(v, 4));
                v = fmaxf(v, __shfl_xor(v, 8));
                mx[rt][r] = v;
            }
        if (l15 == 0) {
            int chunk = cb * 8 + w;
#pragma unroll
            for (int rt = 0; rt < 4; ++rt)
#pragma unroll
                for (int r = 0; r < 4; ++r) {
                    int rowg = b * N_ + rowbase + rt * 16 + lg * 4 + r;
                    rowmax[(size_t)rowg * 128 + chunk] = mx[rt][r];
                }
        }
    } else {
        int blk2 = blk - 256;
        int mat = blk2 >> 6;
        int b = (blk2 >> 5) & 1;
        int r0 = (blk2 & 31) * 16;
        const unsigned short* src = (mat ? w_bf : q_bf) + (size_t)b * N_ * C_;

        __shared__ int s_colids[N_][4];
        __shared__ int s_rowcc[16][16];
        {
            const int4* gsrc = (const int4*)((mat ? wid4 : cid4) + b * N_ * 4);
            ((int4*)s_colids)[tid] = gsrc[tid];
            if (tid < 256)
                ((int*)s_rowcc)[tid] = wcc16[(b * N_ + r0) * 16 + tid];
        }
        short8 a0 = *(const short8*)(src + (size_t)(r0 + l15) * C_ + lg * 8);
        short8 a1 = *(const short8*)(src + (size_t)(r0 + l15) * C_ + 32 + lg * 8);
        short8 a2 = *(const short8*)(src + (size_t)(r0 + l15) * C_ + 64 + lg * 8);
        short8 a3 = *(const short8*)(src + (size_t)(r0 + l15) * C_ + 96 + lg * 8);
        __syncthreads();

        int4 rowc[4];
        int rcc[4][16];
#pragma unroll
        for (int r = 0; r < 4; ++r) {
            rowc[r] = *(const int4*)(&s_colids[r0 + lg * 4 + r][0]);
            if (mat == 1) {
#pragma unroll
                for (int i = 0; i < 16; ++i) rcc[r][i] = s_rowcc[lg * 4 + r][i];
            }
        }

        float* prow = psim + ((size_t)(mat * B_ + b) * N_) * N_;
#pragma unroll
        for (int t = 0; t < 4; ++t) {
            int col0 = w * 64 + t * 16;
            const unsigned short* dp = src + (size_t)(col0 + l15) * C_ + lg * 8;
            short8 b0 = *(const short8*)(dp);
            short8 b1 = *(const short8*)(dp + 32);
            short8 b2 = *(const short8*)(dp + 64);
            short8 b3 = *(const short8*)(dp + 96);
            f32x4 acc4 = {0.0f, 0.0f, 0.0f, 0.0f};
            acc4 = __builtin_amdgcn_mfma_f32_16x16x32_bf16(a0, b0, acc4, 0, 0, 0);
            acc4 = __builtin_amdgcn_mfma_f32_16x16x32_bf16(a1, b1, acc4, 0, 0, 0);
            acc4 = __builtin_amdgcn_mfma_f32_16x16x32_bf16(a2, b2, acc4, 0, 0, 0);
            acc4 = __builtin_amdgcn_mfma_f32_16x16x32_bf16(a3, b3, acc4, 0, 0, 0);
            int mycol = col0 + l15;
            int4 cc = *(const int4*)(&s_colids[mycol][0]);
#pragma unroll
            for (int r = 0; r < 4; ++r) {
                int cnt = 0;
                if (mat == 0) {
#pragma unroll
                    for (int j = 0; j < 4; ++j) {
                        int u = (j == 0) ? rowc[r].x : (j == 1) ? rowc[r].y
                              : (j == 2) ? rowc[r].z : rowc[r].w;
                        cnt += (u == cc.x) + (u == cc.y) + (u == cc.z) + (u == cc.w);
                    }
                } else {
#pragma unroll
                    for (int i = 0; i < 16; ++i) {
                        int u = rcc[r][i];
                        cnt += (u == cc.x) + (u == cc.y) + (u == cc.z) + (u == cc.w);
                    }
                }
                float key = acc4[r] - 2.5f * (float)cnt;
                prow[(size_t)(r0 + lg * 4 + r) * N_ + mycol] = key;
            }
        }
    }
}

// ---------------------------------------------------------------------------
// KC: fused t32 (rank-scan over rowmax, replaces k3b) + survivor pass.
// ---------------------------------------------------------------------------
__global__ __launch_bounds__(512) void hqt_kc(
    const unsigned short* __restrict__ q_bf,
    const unsigned short* __restrict__ d2t,
    const float* __restrict__ rowmax,
    int* __restrict__ scnt, float2* __restrict__ sbuf) {
    int blk = blockIdx.x;
    int b = blk >> 7;
    int rg = (blk >> 4) & 7;
    int cb = blk & 15;
    int tid = threadIdx.x, w = tid >> 6, l = tid & 63;
    int l15 = l & 15, lg = l >> 4;
    int rowbase = rg * 64;
    int colbase = cb * 1024 + w * 128;

    __shared__ float rm[64][128];
    __shared__ float t32_l[64];
    {
        // stage rowmax for this block's 64 rows (8 threads x 16 vals per row)
        int row = tid >> 3, g = tid & 7;
        const float* src = rowmax + ((size_t)(b * N_ + rowbase + row) * 128 + g * 16);
        float4* dst = (float4*)&rm[row][g * 16];
        dst[0] = ((const float4*)src)[0];
        dst[1] = ((const float4*)src)[1];
        dst[2] = ((const float4*)src)[2];
        dst[3] = ((const float4*)src)[3];
    }
    __syncthreads();
    {
        // rank-scan: 32nd largest of each row's 128 window maxima
        int row = tid >> 3, g = tid & 7;
        float cand[16];
        int rk[16];
#pragma unroll
        for (int k = 0; k < 16; ++k) { cand[k] = rm[row][g * 16 + k]; rk[k] = 0; }
        for (int j = 0; j < 128; j += 4) {
            float4 kk = *(const float4*)&rm[row][j];
#pragma unroll
            for (int e = 0; e < 4; ++e) {
                float key = (e == 0) ? kk.x : (e == 1) ? kk.y : (e == 2) ? kk.z : kk.w;
                int jj = j + e;
#pragma unroll
                for (int k = 0; k < 16; ++k)
                    rk[k] += (key > cand[k]) || (key == cand[k] && jj < g * 16 + k);
            }
        }
#pragma unroll
        for (int k = 0; k < 16; ++k)
            if (rk[k] == 31) t32_l[row] = cand[k];
    }
    __syncthreads();

    const unsigned short* qb = q_bf + (size_t)b * N_ * C_;
    const unsigned short* db = d2t + (size_t)b * HW_ * C_;
    short8 a[4][4];
#pragma unroll
    for (int rt = 0; rt < 4; ++rt)
#pragma unroll
        for (int ks = 0; ks < 4; ++ks)
            a[rt][ks] = *(const short8*)(qb + (size_t)(rowbase + rt * 16 + l15) * C_ + ks * 32 + lg * 8);
    float tl[4][4];
#pragma unroll
    for (int rt = 0; rt < 4; ++rt)
#pragma unroll
        for (int r = 0; r < 4; ++r)
            tl[rt][r] = t32_l[rt * 16 + lg * 4 + r];
#pragma unroll
    for (int t = 0; t < 8; ++t) {
        const unsigned short* dp = db + (size_t)(colbase + t * 16 + l15) * C_ + lg * 8;
        short8 b0 = *(const short8*)(dp);
        short8 b1 = *(const short8*)(dp + 32);
        short8 b2 = *(const short8*)(dp + 64);
        short8 b3 = *(const short8*)(dp + 96);
#pragma unroll
        for (int rt = 0; rt < 4; ++rt) {
            f32x4 acc4 = {0.0f, 0.0f, 0.0f, 0.0f};
            acc4 = __builtin_amdgcn_mfma_f32_16x16x32_bf16(a[rt][0], b0, acc4, 0, 0, 0);
            acc4 = __builtin_amdgcn_mfma_f32_16x16x32_bf16(a[rt][1], b1, acc4, 0, 0, 0);
            acc4 = __builtin_amdgcn_mfma_f32_16x16x32_bf16(a[rt][2], b2, acc4, 0, 0, 0);
            acc4 = __builtin_amdgcn_mfma_f32_16x16x32_bf16(a[rt][3], b3, acc4, 0, 0, 0);
#pragma unroll
            for (int r = 0; r < 4; ++r) {
                float d = acc4[r];
                if (d >= tl[rt][r]) {
                    int rowg = b * N_ + rowbase + rt * 16 + lg * 4 + r;
                    int idx = atomicAdd(scnt + rowg, 1);
                    if (idx < SCAP_) {
                        float2 e;
                        e.x = d;
                        e.y = __int_as_float(colbase + t * 16 + l15);
                        sbuf[(size_t)rowg * SCAP_ + idx] = e;
                    }
                }
            }
        }
    }
}

// ---------------------------------------------------------------------------
// KD: [0,256) fos via rank-scan top-16; [256,512) sos via rank-scan top-8.
// Atomic-ticket finalize.
// ---------------------------------------------------------------------------
__global__ __launch_bounds__(256) void hqt_kd(
    const unsigned short* __restrict__ q_bf,
    const unsigned short* __restrict__ d2t,
    const unsigned int* __restrict__ marked,
    const int* __restrict__ scnt, const float2* __restrict__ sbuf,
    const float* __restrict__ pos, const float* __restrict__ psim,
    const int* __restrict__ cid4, const int* __restrict__ wid4,
    const int* __restrict__ wcc16, float* __restrict__ acc,
    float* __restrict__ out) {
    int blk = blockIdx.x;
    int w = threadIdx.x >> 6, l = threadIdx.x & 63;
    if (blk < 256) {
        // ================= fos: exact penalized top-16 via rank-scan ======
        __shared__ float keys[4][160];
        int row = blk * 4 + w;
        int b = row >> 9;
        int sc = scnt[row]; if (sc > SCAP_) sc = SCAP_;
        float k0 = -1e30f, k1 = -1e30f;
        int c0 = -1, c1 = -1;
        if (l < sc) {
            float2 e = sbuf[(size_t)row * SCAP_ + l];
            k0 = e.x; c0 = __float_as_int(e.y);
        }
        if (64 + l < sc) {
            float2 e = sbuf[(size_t)row * SCAP_ + 64 + l];
            k1 = e.x; c1 = __float_as_int(e.y);
        }
#pragma unroll
        for (int i = 0; i < 16; ++i) {
            unsigned int mv = marked[row * 16 + i];
            int id = (int)(mv & 0xFFFFu);
            if (c0 == id) k0 = -1e30f;
            if (c1 == id) k1 = -1e30f;
        }
        // marked keys (exact, 4 lanes per marked slot)
        float k2c = -1e30f;
        int mi = l >> 2;
        {
            int cq = l & 3;
            unsigned int mv = marked[row * 16 + mi];
            bool valid = (mv != 0xFFFFFFFFu);
            int col = valid ? (int)(mv & 0xFFFFu) : 0;
            int cnt = (int)(mv >> 16);
            const unsigned short* qp = q_bf + (size_t)row * C_ + cq * 32;
            const unsigned short* dp = d2t + ((size_t)b * HW_ + col) * C_ + cq * 32;
            float dot = 0.0f;
#pragma unroll
            for (int u = 0; u < 4; ++u) {
                short8 qv = *(const short8*)(qp + u * 8);
                short8 dv = *(const short8*)(dp + u * 8);
#pragma unroll
                for (int e = 0; e < 8; ++e)
                    dot = fmaf(bf2f((unsigned short)qv[e]), bf2f((unsigned short)dv[e]), dot);
            }
            dot += __shfl_xor(dot, 1);
            dot += __shfl_xor(dot, 2);
            k2c = valid ? (dot - 2.5f * (float)cnt) : -1e30f;
            // stage keys
            keys[w][l] = k0;
            keys[w][64 + l] = k1;
            if (cq == 0) keys[w][128 + mi] = k2c;
            if (l < 16) keys[w][144 + l] = -1e30f;   // pad
        }
        __syncthreads();
        // rank-scan: candidates (k0@l), (k1@64+l), (k2c@128+l for l<16)
        float cC = (l < 16) ? keys[w][128 + l] : -1e30f;
        int idxC = 128 + l;
        int r0 = 0, r1 = 0, r2 = 0;
        for (int j = 0; j < 144; j += 4) {
            float4 kk = *(const float4*)&keys[w][j];
#pragma unroll
            for (int e = 0; e < 4; ++e) {
                float key = (e == 0) ? kk.x : (e == 1) ? kk.y : (e == 2) ? kk.z : kk.w;
                int jj = j + e;
                r0 += (key > k0) || (key == k0 && jj < l);
                r1 += (key > k1) || (key == k1 && jj < 64 + l);
                r2 += (key > cC) || (key == cC && jj < idxC);
            }
        }
        float pos_r = pos[row];
        float sum = 0.0f;
        if (r0 < 16) { float h = fmaxf(pos_r + 2.0f * k0 - 1.0f, 0.0f); sum += h * h; }
        if (r1 < 16) { float h = fmaxf(pos_r + 2.0f * k1 - 1.0f, 0.0f); sum += h * h; }
        if (r2 < 16) { float h = fmaxf(pos_r + 2.0f * cC - 1.0f, 0.0f); sum += h * h; }
        sum += __shfl_xor(sum, 1);  sum += __shfl_xor(sum, 2);
        sum += __shfl_xor(sum, 4);  sum += __shfl_xor(sum, 8);
        sum += __shfl_xor(sum, 16); sum += __shfl_xor(sum, 32);
        if (l == 0) atomicAdd(acc + 0, sum);
    } else {
        // ================= sos: rank-scan top-8 per (row, mat) ============
        __shared__ float cand[4][128];
        __shared__ float sval[4][64];
        __shared__ int   scol[4][64];
        __shared__ int   cnt_l[4];
        __shared__ float tpp[4];
        __shared__ float sel[4][2][8];
        int rowg = (blk - 256) * 4 + w;
        int b = rowg >> 9;
        int row = rowg & 511;
#pragma unroll 1
        for (int mat = 0; mat < 2; ++mat) {
            const float* pr = psim + ((size_t)(mat * B_ + b) * N_ + row) * N_;
            float4 u0 = ((const float4*)pr)[l * 2];
            float4 u1 = ((const float4*)pr)[l * 2 + 1];
            float k[8] = {u0.x, u0.y, u0.z, u0.w, u1.x, u1.y, u1.z, u1.w};
            // per-lane top-2 (values only)
            float m1 = -1e30f, m2 = -1e30f;
#pragma unroll
            for (int i = 0; i < 8; ++i) {
                float v = k[i];
                bool g1 = v > m1;
                m2 = g1 ? m1 : fmaxf(m2, v);
                m1 = g1 ? v : m1;
            }
            if (l == 0) cnt_l[w] = 0;
            cand[w][l] = m1;
            cand[w][64 + l] = m2;
            __syncthreads();
            // t8' = 8th largest of the 128-set (strict by value, then slot)
            int rA = 0, rB = 0;
            for (int j = 0; j < 128; j += 4) {
                float4 cc = *(const float4*)&cand[w][j];
#pragma unroll
                for (int e = 0; e < 4; ++e) {
                    float cv = (e == 0) ? cc.x : (e == 1) ? cc.y : (e == 2) ? cc.z : cc.w;
                    int jj = j + e;
                    rA += (cv > m1) || (cv == m1 && jj < l);
                    rB += (cv > m2) || (cv == m2 && jj < 64 + l);
                }
            }
            if (rA == 7) tpp[w] = m1;
            if (rB == 7) tpp[w] = m2;
            __syncthreads();
            float t8 = tpp[w];
            // survivors (v >= t8 by value) -> LDS via atomic ticket
#pragma unroll
            for (int i = 0; i < 8; ++i) {
                if (k[i] >= t8) {
                    int s = atomicAdd(&cnt_l[w], 1);
                    if (s < 64) { sval[w][s] = k[i]; scol[w][s] = l * 8 + i; }
                }
            }
            __syncthreads();
            int cnt = cnt_l[w]; if (cnt > 64) cnt = 64;
            // rank survivors: (value desc, col asc) == lax.top_k order
            float sv = (l < cnt) ? sval[w][l] : -1e30f;
            int   scm = (l < cnt) ? scol[w][l] : INT_MAX;
            int r = 0;
            for (int j = 0; j < cnt; ++j) {
                float vj = sval[w][j];
                int cj = scol[w][j];
                r += (vj > sv) || (vj == sv && cj < scm);
            }
            if (l < cnt && r < 8) {
                // reconstruct clean dot: key + 2.5 * exact mask count
                int cntm = 0;
                if (mat == 0) {
                    const int4* cb4 = (const int4*)(cid4 + b * N_ * 4);
                    int4 rc = cb4[row];
                    int4 mc = cb4[scm];
#pragma unroll
                    for (int j = 0; j < 4; ++j) {
                        int u = (j == 0) ? rc.x : (j == 1) ? rc.y : (j == 2) ? rc.z : rc.w;
                        cntm += (u == mc.x) + (u == mc.y) + (u == mc.z) + (u == mc.w);
                    }
                } else {
                    const int4* wb4 = (const int4*)(wid4 + b * N_ * 4);
                    int4 mw = wb4[scm];
                    const int4* rcc = (const int4*)(wcc16 + (b * N_ + row) * 16);
#pragma unroll
                    for (int uq = 0; uq < 4; ++uq) {
                        int4 rr = rcc[uq];
                        cntm += (rr.x == mw.x) + (rr.x == mw.y) + (rr.x == mw.z) + (rr.x == mw.w);
                        cntm += (rr.y == mw.x) + (rr.y == mw.y) + (rr.y == mw.z) + (rr.y == mw.w);
                        cntm += (rr.z == mw.x) + (rr.z == mw.y) + (rr.z == mw.z) + (rr.z == mw.w);
                        cntm += (rr.w == mw.x) + (rr.w == mw.y) + (rr.w == mw.z) + (rr.w == mw.w);
                    }
                }
                sel[w][mat][r] = sv + 2.5f * (float)cntm;
            }
            __syncthreads();
        }
        if (l < 8) {
            float t2 = 2.0f * (sel[w][1][l] - sel[w][0][l]);
            float sq = t2 * t2;
            sq += __shfl_xor(sq, 1);
            sq += __shfl_xor(sq, 2);
            sq += __shfl_xor(sq, 4);
            if (l == 0) atomicAdd(acc + 1, sqrtf(sq));
        }
    }
    // ---- ticket finalize ----
    __syncthreads();
    if (threadIdx.x == 0) {
        __threadfence();
        unsigned int t = atomicAdd((unsigned int*)(acc + 2), 1u);
        if (t == 511u) {
            float a0 = atomicAdd(acc + 0, 0.0f);
            float a1 = atomicAdd(acc + 1, 0.0f);
            out[0] = a0 * (1.0f / (float)(B_ * N_ * NUM_NEG_))
                   + a1 * (1.0f / (float)(B_ * N_));
        }
    }
}

// ======================= fallback (round-1) kernels ========================
__global__ void hqt_k1_cells(const float* __restrict__ kp1,
                             const float* __restrict__ w_kp1,
                             const float* __restrict__ homo,
                             int* __restrict__ cid4,
                             int* __restrict__ wcc16,
                             int* __restrict__ wid4) {
    int t = blockIdx.x * blockDim.x + threadIdx.x;
    if (t >= B_ * N_) return;
    int b = t / N_;
    float ky = kp1[2 * t], kx = kp1[2 * t + 1];
    int ids[4];
    nearest4(ky, kx, ids);
    const float* Hb = homo + 9 * b;
    float h00 = Hb[0], h01 = Hb[1], h02 = Hb[2];
    float h10 = Hb[3], h11 = Hb[4], h12 = Hb[5];
    float h20 = Hb[6], h21 = Hb[7], h22 = Hb[8];
#pragma unroll
    for (int i = 0; i < 4; ++i) {
        int id = ids[i];
        cid4[4 * t + i] = id;
        float cy = 8.0f * (id >> 7) + 4.0f;
        float cx = 8.0f * (id & 127) + 4.0f;
        float X = cx, Y = cy;
        float wz = h20 * X + h21 * Y + h22;
        float inv = 1.0f / (wz + 1e-8f);
        float wy = (h10 * X + h11 * Y + h12) * inv;
        float wx = (h00 * X + h01 * Y + h02) * inv;
        int wids[4];
        nearest4(wy, wx, wids);
#pragma unroll
        for (int j = 0; j < 4; ++j) wcc16[16 * t + 4 * i + j] = wids[j];
    }
    float zy = w_kp1[2 * t], zx = w_kp1[2 * t + 1];
    int wi4[4];
    nearest4(zy, zx, wi4);
#pragma unroll
    for (int j = 0; j < 4; ++j) wid4[4 * t + j] = wi4[j];
}

__global__ __launch_bounds__(128) void hqt_k2_sample_f32(
    const float* __restrict__ w_kp1, const float* __restrict__ desc2,
    const float* __restrict__ kp1_desc, float* __restrict__ w_desc,
    float* __restrict__ pos) {
    int bn = blockIdx.x;
    int b = bn / N_;
    int c = threadIdx.x;
    float ky = w_kp1[2 * bn], kx = w_kp1[2 * bn + 1];
    float y = fminf(fmaxf(ky * 0.125f - 0.5f, 0.0f), (float)(H_ - 1));
    float x = fminf(fmaxf(kx * 0.125f - 0.5f, 0.0f), (float)(W_ - 1));
    int y0 = (int)floorf(y); if (y0 > H_ - 2) y0 = H_ - 2;
    int x0 = (int)floorf(x); if (x0 > W_ - 2) x0 = W_ - 2;
    float wy = y - (float)y0, wx = x - (float)x0;
    const float* dB = desc2 + ((size_t)b * C_ + c) * HW_;
    int i00 = y0 * W_ + x0;
    float v = dB[i00]          * (1.0f - wy) * (1.0f - wx)
            + dB[i00 + 1]      * (1.0f - wy) * wx
            + dB[i00 + W_]     * wy * (1.0f - wx)
            + dB[i00 + W_ + 1] * wy * wx;
    __shared__ float red[128];
    red[c] = v * v;
    __syncthreads();
    for (int s = 64; s > 0; s >>= 1) {
        if (c < s) red[c] += red[c + s];
        __syncthreads();
    }
    float nrm = sqrtf(red[0]);
    __syncthreads();
    float vn = v / (nrm + 1e-8f);
    w_desc[(size_t)bn * C_ + c] = vn;
    float qd = kp1_desc[(size_t)bn * C_ + c];
    red[c] = qd * vn;
    __syncthreads();
    for (int s = 64; s > 0; s >>= 1) {
        if (c < s) red[c] += red[c + s];
        __syncthreads();
    }
    if (c == 0) pos[bn] = 2.0f - 2.0f * red[0];
}

__device__ inline void insert8_vi(float (&av)[8], int (&ai)[8], float v, int id) {
    bool le = (v < av[7]) || (v == av[7] && id < ai[7]);
    if (!le) return;
#pragma unroll
    for (int k = 0; k < 8; ++k) {
        float ov = av[k]; int oi = ai[k];
        bool sm = (v < ov) || (v == ov && id < oi);
        av[k] = sm ? v : ov;  ai[k] = sm ? id : oi;
        v = sm ? ov : v;      id = sm ? oi : id;
    }
}

__device__ inline void bitonic8_pairs(float (&av)[8], int (&ai)[8]) {
#pragma unroll
    for (int dd = 0; dd < 3; ++dd) {
        const int d = 4 >> dd;
#pragma unroll
        for (int i = 0; i < 8; ++i) {
            if ((i & d) == 0) {
                bool sw = (av[i + d] < av[i]) ||
                          (av[i + d] == av[i] && ai[i + d] < ai[i]);
                float tv = av[i]; int ti = ai[i];
                av[i]     = sw ? av[i + d] : av[i];
                ai[i]     = sw ? ai[i + d] : ai[i];
                av[i + d] = sw ? tv : av[i + d];
                ai[i + d] = sw ? ti : ai[i + d];
            }
        }
    }
}

__device__ inline void bitonic16_asc(float (&a)[16]) {
#pragma unroll
    for (int dd = 0; dd < 4; ++dd) {
        const int d = 8 >> dd;
#pragma unroll
        for (int i = 0; i < 16; ++i) {
            if ((i & d) == 0) {
                float lo = fminf(a[i], a[i + d]);
                float hi = fmaxf(a[i], a[i + d]);
                a[i] = lo; a[i + d] = hi;
            }
        }
    }
}

#define T3 512
#define R3 4
__global__ __launch_bounds__(T3) void hqt_k3_dsim(
    const float* __restrict__ desc2, const float* __restrict__ kp1_desc,
    const int* __restrict__ wcc16, const float* __restrict__ pos,
    float* __restrict__ acc) {
    const int nb = N_ / R3;
    int b = blockIdx.x / nb;
    int n0 = (blockIdx.x % nb) * R3;
    int tid = threadIdx.x;
    __shared__ float qT[C_][R3];
    __shared__ int ids_s[R3][16];
    {
        int r = tid & 3, c = tid >> 2;
        qT[c][r] = kp1_desc[(size_t)(b * N_ + n0 + r) * C_ + c];
    }
    if (tid < R3 * 16)
        ids_s[tid >> 4][tid & 15] = wcc16[(b * N_ + n0) * 16 + tid];
    __syncthreads();

    float top[R3][16];
#pragma unroll
    for (int r = 0; r < R3; ++r)
#pragma unroll
        for (int k = 0; k < 16; ++k) top[r][k] = 1e30f;

    const float* d2b = desc2 + (size_t)b * C_ * HW_;
#pragma unroll 1
    for (int g = 0; g < HW_ / (T3 * 4); ++g) {
        int j0 = (g * T3 + tid) * 4;
        float4 A0 = {0, 0, 0, 0}, A1 = {0, 0, 0, 0}, A2 = {0, 0, 0, 0}, A3 = {0, 0, 0, 0};
        for (int c = 0; c < C_; ++c) {
            float4 d = *reinterpret_cast<const float4*>(d2b + (size_t)c * HW_ + j0);
            float4 qv = *reinterpret_cast<const float4*>(&qT[c][0]);
            A0.x = fmaf(qv.x, d.x, A0.x); A0.y = fmaf(qv.x, d.y, A0.y);
            A0.z = fmaf(qv.x, d.z, A0.z); A0.w = fmaf(qv.x, d.w, A0.w);
            A1.x = fmaf(qv.y, d.x, A1.x); A1.y = fmaf(qv.y, d.y, A1.y);
            A1.z = fmaf(qv.y, d.z, A1.z); A1.w = fmaf(qv.y, d.w, A1.w);
            A2.x = fmaf(qv.z, d.x, A2.x); A2.y = fmaf(qv.z, d.y, A2.y);
            A2.z = fmaf(qv.z, d.z, A2.z); A2.w = fmaf(qv.z, d.w, A2.w);
            A3.x = fmaf(qv.w, d.x, A3.x); A3.y = fmaf(qv.w, d.y, A3.y);
            A3.z = fmaf(qv.w, d.z, A3.z); A3.w = fmaf(qv.w, d.w, A3.w);
        }
#pragma unroll
        for (int r = 0; r < R3; ++r) {
            float dots[4];
            dots[0] = (r == 0) ? A0.x : (r == 1) ? A1.x : (r == 2) ? A2.x : A3.x;
            dots[1] = (r == 0) ? A0.y : (r == 1) ? A1.y : (r == 2) ? A2.y : A3.y;
            dots[2] = (r == 0) ? A0.z : (r == 1) ? A1.z : (r == 2) ? A2.z : A3.z;
            dots[3] = (r == 0) ? A0.w : (r == 1) ? A1.w : (r == 2) ? A2.w : A3.w;
#pragma unroll
            for (int cc = 0; cc < 4; ++cc) {
                int j = j0 + cc;
                int cnt = 0;
#pragma unroll
                for (int i = 0; i < 16; ++i) cnt += (ids_s[r][i] == j) ? 1 : 0;
                float v = 2.0f - 2.0f * dots[cc] + 5.0f * (float)cnt;
                if (v < top[r][15]) {
#pragma unroll
                    for (int k = 0; k < 16; ++k) {
                        float o = top[r][k];
                        bool sm = v < o;
                        top[r][k] = sm ? v : o;
                        v = sm ? o : v;
                    }
                }
            }
        }
    }

    __shared__ float mv[T3][17];
#pragma unroll
    for (int r = 0; r < R3; ++r) {
        float a[16];
#pragma unroll
        for (int k = 0; k < 16; ++k) { a[k] = top[r][k]; mv[tid][k] = a[k]; }
        __syncthreads();
        for (int step = T3 / 2; step >= 1; step >>= 1) {
            if (tid < step) {
#pragma unroll
                for (int i = 0; i < 16; ++i)
                    a[i] = fminf(a[i], mv[tid + step][15 - i]);
                bitonic16_asc(a);
#pragma unroll
                for (int i = 0; i < 16; ++i) mv[tid][i] = a[i];
            }
            __syncthreads();
        }
        if (tid == 0) {
            float p = pos[b * N_ + n0 + r];
            float s = 0.0f;
#pragma unroll
            for (int k = 0; k < 16; ++k) {
                float xv = p - a[k] + 1.0f;
                xv = fmaxf(xv, 0.0f);
                s += xv * xv;
            }
            atomicAdd(acc + 0, s);
        }
        __syncthreads();
    }
}

__global__ __launch_bounds__(64) void hqt_k4_sos(
    const float* __restrict__ kp1_desc, const float* __restrict__ w_desc,
    const int* __restrict__ cid4, const int* __restrict__ wcc16,
    const int* __restrict__ wid4, float* __restrict__ acc) {
    int bn = blockIdx.x;
    int b = bn / N_;
    int lane = threadIdx.x;
    __shared__ float qk[C_], qw[C_];
    for (int c = lane; c < C_; c += 64) {
        qk[c] = kp1_desc[(size_t)bn * C_ + c];
        qw[c] = w_desc[(size_t)bn * C_ + c];
    }
    __syncthreads();
    int nk[4];
#pragma unroll
    for (int i = 0; i < 4; ++i) nk[i] = cid4[4 * bn + i];
    int nw[16];
#pragma unroll
    for (int i = 0; i < 16; ++i) nw[i] = wcc16[16 * bn + i];

    float kv[8], wv[8]; int ki[8], wi[8];
#pragma unroll
    for (int k = 0; k < 8; ++k) {
        kv[k] = 1e30f; wv[k] = 1e30f; ki[k] = INT_MAX; wi[k] = INT_MAX;
    }
    const float* kb = kp1_desc + (size_t)b * N_ * C_;
    const float* wb = w_desc + (size_t)b * N_ * C_;
    for (int tt = 0; tt < 8; ++tt) {
        int m = lane * 8 + tt;
        const float* rk = kb + (size_t)m * C_;
        const float* rw = wb + (size_t)m * C_;
        float dk = 0.0f, dw = 0.0f;
        for (int c = 0; c < C_; c += 4) {
            float4 xk = *(const float4*)(rk + c);
            float4 xw = *(const float4*)(rw + c);
            dk += qk[c] * xk.x + qk[c + 1] * xk.y + qk[c + 2] * xk.z + qk[c + 3] * xk.w;
            dw += qw[c] * xw.x + qw[c + 1] * xw.y + qw[c + 2] * xw.z + qw[c + 3] * xw.w;
        }
        int4 mc = *(const int4*)(cid4 + 4 * (b * N_ + m));
        int ck = 0;
#pragma unroll
        for (int i = 0; i < 4; ++i) {
            int u = nk[i];
            ck += (u == mc.x) + (u == mc.y) + (u == mc.z) + (u == mc.w);
        }
        int4 mw = *(const int4*)(wid4 + 4 * (b * N_ + m));
        int cw = 0;
#pragma unroll
        for (int i = 0; i < 16; ++i) {
            int u = nw[i];
            cw += (u == mw.x) + (u == mw.y) + (u == mw.z) + (u == mw.w);
        }
        float vk = 2.0f - 2.0f * dk + 5.0f * (float)ck;
        float vw2 = 2.0f - 2.0f * dw + 5.0f * (float)cw;
        insert8_vi(kv, ki, vk, m);
        insert8_vi(wv, wi, vw2, m);
    }

    __shared__ float mvs[64][9];
    __shared__ int mis[64][9];
    __shared__ int fk[8], fw[8];

#pragma unroll
    for (int i = 0; i < 8; ++i) { mvs[lane][i] = kv[i]; mis[lane][i] = ki[i]; }
    __syncthreads();
    for (int step = 32; step >= 1; step >>= 1) {
        if (lane < step) {
            float bv[8]; int bix[8];
#pragma unroll
            for (int i = 0; i < 8; ++i) {
                bv[i] = mvs[lane + step][7 - i];
                bix[i] = mis[lane + step][7 - i];
            }
#pragma unroll
            for (int i = 0; i < 8; ++i) {
                bool ta = (kv[i] < bv[i]) || (kv[i] == bv[i] && ki[i] < bix[i]);
                kv[i] = ta ? kv[i] : bv[i];
                ki[i] = ta ? ki[i] : bix[i];
            }
            bitonic8_pairs(kv, ki);
#pragma unroll
            for (int i = 0; i < 8; ++i) { mvs[lane][i] = kv[i]; mis[lane][i] = ki[i]; }
        }
        __syncthreads();
    }
    if (lane < 8) fk[lane] = mis[0][lane];
    __syncthreads();

#pragma unroll
    for (int i = 0; i < 8; ++i) { mvs[lane][i] = wv[i]; mis[lane][i] = wi[i]; }
    __syncthreads();
    for (int step = 32; step >= 1; step >>= 1) {
        if (lane < step) {
            float bv[8]; int bix[8];
#pragma unroll
            for (int i = 0; i < 8; ++i) {
                bv[i] = mvs[lane + step][7 - i];
                bix[i] = mis[lane + step][7 - i];
            }
#pragma unroll
            for (int i = 0; i < 8; ++i) {
                bool ta = (wv[i] < bv[i]) || (wv[i] == bv[i] && wi[i] < bix[i]);
                wv[i] = ta ? wv[i] : bv[i];
                wi[i] = ta ? wi[i] : bix[i];
            }
            bitonic8_pairs(wv, wi);
#pragma unroll
            for (int i = 0; i < 8; ++i) { mvs[lane][i] = wv[i]; mis[lane][i] = wi[i]; }
        }
        __syncthreads();
    }
    if (lane < 8) fw[lane] = mis[0][lane];
    __syncthreads();

    int s = lane >> 3, p = lane & 7;
    const float* rk = kb + (size_t)fk[s] * C_;
    const float* rw = wb + (size_t)fw[s] * C_;
    float dk = 0.0f, dw = 0.0f;
    for (int c = p; c < C_; c += 8) {
        dk += qk[c] * rk[c];
        dw += qw[c] * rw[c];
    }
    dk += __shfl_xor(dk, 1); dk += __shfl_xor(dk, 2); dk += __shfl_xor(dk, 4);
    dw += __shfl_xor(dw, 1); dw += __shfl_xor(dw, 2); dw += __shfl_xor(dw, 4);
    __shared__ float tsq[8];
    if (p == 0) {
        float t2 = 2.0f * (dw - dk);
        tsq[s] = t2 * t2;
    }
    __syncthreads();
    if (lane == 0) {
        float s8 = 0.0f;
#pragma unroll
        for (int i = 0; i < 8; ++i) s8 += tsq[i];
        atomicAdd(acc + 1, sqrtf(s8));
    }
}

__global__ void hqt_k5_final(const float* __restrict__ acc, float* __restrict__ out) {
    if (threadIdx.x == 0 && blockIdx.x == 0) {
        out[0] = acc[0] * (1.0f / (float)(B_ * N_ * NUM_NEG_))
               + acc[1] * (1.0f / (float)(B_ * N_));
    }
}

// ===========================================================================
extern "C" void kernel_launch(void* const* d_in, const int* in_sizes, int n_in,
                              void* d_out, int out_size, void* d_ws, size_t ws_size,
                              hipStream_t stream) {
    const float* kp1      = (const float*)d_in[0];
    const float* w_kp1    = (const float*)d_in[1];
    const float* kp1_desc = (const float*)d_in[2];
    const float* desc2    = (const float*)d_in[3];
    const float* homo     = (const float*)d_in[4];
    float* out = (float*)d_out;

    char* p = (char*)d_ws;
    auto alloc = [&](size_t bytes) {
        char* r = p;
        p += (bytes + 255) & ~(size_t)255;
        return r;
    };
    float*          pos    = (float*)alloc((size_t)B_ * N_ * 4);
    int*            cid4   = (int*)alloc((size_t)B_ * N_ * 4 * 4);
    int*            wid4   = (int*)alloc((size_t)B_ * N_ * 4 * 4);
    int*            wcc16  = (int*)alloc((size_t)B_ * N_ * 16 * 4);
    unsigned int*   marked = (unsigned int*)alloc((size_t)B_ * N_ * 16 * 4);
    float*          acc    = (float*)alloc(64);
    unsigned short* q_bf   = (unsigned short*)alloc((size_t)B_ * N_ * C_ * 2);
    unsigned short* w_bf   = (unsigned short*)alloc((size_t)B_ * N_ * C_ * 2);
    unsigned short* d2t    = (unsigned short*)alloc((size_t)B_ * HW_ * C_ * 2);
    float*          psim   = (float*)alloc((size_t)2 * B_ * N_ * N_ * 4);
    float*          rowmax = (float*)alloc((size_t)B_ * N_ * 128 * 4);
    int*            scnt   = (int*)alloc((size_t)B_ * N_ * 4);
    float2*         sbuf   = (float2*)alloc((size_t)B_ * N_ * SCAP_ * 8);
    size_t need = (size_t)(p - (char*)d_ws);

    if (ws_size >= need) {
        hqt_ka<<<1413, 256, 0, stream>>>(desc2, kp1_desc, kp1, w_kp1, homo,
                                         d2t, q_bf, w_bf, pos, cid4, wcc16,
                                         wid4, marked, scnt, acc);
        hqt_kb<<<384, 512, 0, stream>>>(q_bf, w_bf, d2t, cid4, wid4, wcc16,
                                        rowmax, psim);
        hqt_kc<<<256, 512, 0, stream>>>(q_bf, d2t, rowmax, scnt, sbuf);
        hqt_kd<<<512, 256, 0, stream>>>(q_bf, d2t, marked, scnt, sbuf, pos,
                                        psim, cid4, wid4, wcc16, acc, out);
    } else {
        // fallback: round-1 layout and path
        float* w_desc0 = (float*)d_ws;
        float* pos0    = w_desc0 + (size_t)B_ * N_ * C_;
        int*   cid40   = (int*)(pos0 + B_ * N_);
        int*   wid40   = cid40 + B_ * N_ * 4;
        int*   wcc160  = wid40 + B_ * N_ * 4;
        float* acc0    = (float*)(wcc160 + B_ * N_ * 16);
        hipMemsetAsync(acc0, 0, 2 * sizeof(float), stream);
        hqt_k1_cells<<<(B_ * N_ + 255) / 256, 256, 0, stream>>>(
            kp1, w_kp1, homo, cid40, wcc160, wid40);
        hqt_k2_sample_f32<<<B_ * N_, 128, 0, stream>>>(w_kp1, desc2, kp1_desc,
                                                       w_desc0, pos0);
        hqt_k3_dsim<<<B_ * (N_ / R3), T3, 0, stream>>>(desc2, kp1_desc, wcc160,
                                                       pos0, acc0);
        hqt_k4_sos<<<B_ * N_, 64, 0, stream>>>(kp1_desc, w_desc0, cid40,
                                               wcc160, wid40, acc0);
        hqt_k5_final<<<1, 1, 0, stream>>>(acc0, out);
    }
}

// Round 8
// 134.298 us; speedup vs baseline: 1.5494x; 1.5494x over previous
//
#include <hip/hip_runtime.h>
#include <climits>

#define B_ 2
#define N_ 512
#define C_ 128
#define H_ 128
#define W_ 128
#define HW_ (H_ * W_)
#define NUM_NEG_ 16
#define SOS_NEG_ 8
#define SCAP_ 128   // survivor cap per row

typedef __attribute__((ext_vector_type(8))) short short8;
typedef __attribute__((ext_vector_type(4))) float f32x4;

__device__ inline unsigned int f2bf(float x) {
    unsigned int u = __float_as_uint(x);
    return (u + 0x7FFFu + ((u >> 16) & 1u)) >> 16;
}
__device__ inline float bf2f(unsigned int h) {
    return __uint_as_float(h << 16);
}

// ---------------------------------------------------------------------------
// 4 nearest grid-cell centers of point (y,x); tie-break matches lax.top_k.
// ---------------------------------------------------------------------------
__device__ inline void nearest4(float y, float x, int out[4]) {
    y = fminf(fmaxf(y, -1e6f), 1e6f);
    x = fminf(fmaxf(x, -1e6f), 1e6f);
    int fy = (int)floorf(y * 0.125f - 0.5f);
    int fx = (int)floorf(x * 0.125f - 0.5f);
    int ylo = fy - 1; if (ylo < 0) ylo = 0; if (ylo > H_ - 4) ylo = H_ - 4;
    int xlo = fx - 1; if (xlo < 0) xlo = 0; if (xlo > W_ - 4) xlo = W_ - 4;
    float bd[4] = {1e30f, 1e30f, 1e30f, 1e30f};
    int   bi[4] = {INT_MAX, INT_MAX, INT_MAX, INT_MAX};
#pragma unroll
    for (int dyi = 0; dyi < 4; ++dyi) {
        int yi = ylo + dyi;
        float dy = y - (8.0f * yi + 4.0f);
        float dy2 = dy * dy;
#pragma unroll
        for (int dxi = 0; dxi < 4; ++dxi) {
            int xi = xlo + dxi;
            float dx = x - (8.0f * xi + 4.0f);
            float d = dy2 + dx * dx;
            int id = yi * W_ + xi;
#pragma unroll
            for (int k = 0; k < 4; ++k) {
                bool sm = (d < bd[k]) || (d == bd[k] && id < bi[k]);
                float od = bd[k]; int oi = bi[k];
                bd[k] = sm ? d : od;  bi[k] = sm ? id : oi;
                d = sm ? od : d;      id = sm ? oi : id;
            }
        }
    }
    out[0] = bi[0]; out[1] = bi[1]; out[2] = bi[2]; out[3] = bi[3];
}

__device__ inline void k1_body(int t, const float* kp1, const float* w_kp1,
                               const float* homo, int* cid4, int* wcc16,
                               int* wid4, unsigned int* marked) {
    int b = t / N_;
    float ky = kp1[2 * t], kx = kp1[2 * t + 1];
    int ids[4];
    nearest4(ky, kx, ids);
    const float* Hb = homo + 9 * b;
    float h00 = Hb[0], h01 = Hb[1], h02 = Hb[2];
    float h10 = Hb[3], h11 = Hb[4], h12 = Hb[5];
    float h20 = Hb[6], h21 = Hb[7], h22 = Hb[8];
    int w16[16];
#pragma unroll
    for (int i = 0; i < 4; ++i) {
        int id = ids[i];
        cid4[4 * t + i] = id;
        float cy = 8.0f * (id >> 7) + 4.0f;
        float cx = 8.0f * (id & 127) + 4.0f;
        float X = cx, Y = cy;
        float wz = h20 * X + h21 * Y + h22;
        float inv = 1.0f / (wz + 1e-8f);
        float wy = (h10 * X + h11 * Y + h12) * inv;
        float wx = (h00 * X + h01 * Y + h02) * inv;
        int wids[4];
        nearest4(wy, wx, wids);
#pragma unroll
        for (int j = 0; j < 4; ++j) {
            w16[4 * i + j] = wids[j];
            wcc16[16 * t + 4 * i + j] = wids[j];
        }
    }
#pragma unroll
    for (int i = 0; i < 16; ++i) {
        int cnt = 0; bool first = true;
#pragma unroll
        for (int j = 0; j < 16; ++j) {
            bool eq = (w16[j] == w16[i]);
            cnt += eq ? 1 : 0;
            if (j < i && eq) first = false;
        }
        marked[16 * t + i] = first ? ((unsigned int)w16[i] | ((unsigned int)cnt << 16))
                                   : 0xFFFFFFFFu;
    }
    float zy = w_kp1[2 * t], zx = w_kp1[2 * t + 1];
    int wi4[4];
    nearest4(zy, zx, wi4);
#pragma unroll
    for (int j = 0; j < 4; ++j) wid4[4 * t + j] = wi4[j];
}

// ---------------------------------------------------------------------------
// KA fused: [0,1024) d2t transpose; [1024,1152) q_bf; 1152 zero scnt/acc;
// [1153,1157) k1; [1157,1413) k2 (wave-per-keypoint, shfl-only).
// ---------------------------------------------------------------------------
__global__ __launch_bounds__(256) void hqt_ka(
    const float* __restrict__ desc2, const float* __restrict__ kp1_desc,
    const float* __restrict__ kp1, const float* __restrict__ w_kp1,
    const float* __restrict__ homo,
    unsigned short* __restrict__ d2t, unsigned short* __restrict__ q_bf,
    unsigned short* __restrict__ w_bf, float* __restrict__ pos,
    int* __restrict__ cid4, int* __restrict__ wcc16, int* __restrict__ wid4,
    unsigned int* __restrict__ marked, int* __restrict__ scnt,
    float* __restrict__ acc) {
    int blk = blockIdx.x;
    int tid = threadIdx.x;
    if (blk < 1024) {
        __shared__ float tile[32][129];
        int b = blk >> 9;
        int j0 = (blk & 511) * 32;
        int jj = tid & 31, cg = tid >> 5;
        const float* src = desc2 + (size_t)b * C_ * HW_;
#pragma unroll
        for (int cc = 0; cc < 16; ++cc) {
            int c = cg * 16 + cc;
            tile[jj][c] = src[(size_t)c * HW_ + j0 + jj];
        }
        __syncthreads();
        int row = tid >> 3, c8 = (tid & 7) * 16;
        unsigned int tmp[16];
#pragma unroll
        for (int k = 0; k < 16; ++k) tmp[k] = f2bf(tile[row][c8 + k]);
        uint4 o0, o1;
        o0.x = tmp[0] | (tmp[1] << 16);  o0.y = tmp[2] | (tmp[3] << 16);
        o0.z = tmp[4] | (tmp[5] << 16);  o0.w = tmp[6] | (tmp[7] << 16);
        o1.x = tmp[8] | (tmp[9] << 16);  o1.y = tmp[10] | (tmp[11] << 16);
        o1.z = tmp[12] | (tmp[13] << 16); o1.w = tmp[14] | (tmp[15] << 16);
        unsigned short* dst = d2t + ((size_t)(b << 14) + j0 + row) * C_ + c8;
        ((uint4*)dst)[0] = o0;
        ((uint4*)dst)[1] = o1;
    } else if (blk < 1152) {
        int idx = (blk - 1024) * 256 + tid;
        float4 v = *(const float4*)(kp1_desc + (size_t)idx * 4);
        uint2 u;
        u.x = f2bf(v.x) | (f2bf(v.y) << 16);
        u.y = f2bf(v.z) | (f2bf(v.w) << 16);
        *(uint2*)(q_bf + (size_t)idx * 4) = u;
    } else if (blk == 1152) {
        ((int4*)scnt)[tid] = make_int4(0, 0, 0, 0);
        if (tid == 0) { acc[0] = 0.0f; acc[1] = 0.0f; acc[2] = 0.0f; acc[3] = 0.0f; }
    } else if (blk < 1157) {
        int t = (blk - 1153) * 256 + tid;
        if (t < B_ * N_)
            k1_body(t, kp1, w_kp1, homo, cid4, wcc16, wid4, marked);
    } else {
        int w = tid >> 6, l = tid & 63;
        int bn = (blk - 1157) * 4 + w;
        int b = bn / N_;
        float ky = w_kp1[2 * bn], kx = w_kp1[2 * bn + 1];
        float y = fminf(fmaxf(ky * 0.125f - 0.5f, 0.0f), (float)(H_ - 1));
        float x = fminf(fmaxf(kx * 0.125f - 0.5f, 0.0f), (float)(W_ - 1));
        int y0 = (int)floorf(y); if (y0 > H_ - 2) y0 = H_ - 2;
        int x0 = (int)floorf(x); if (x0 > W_ - 2) x0 = W_ - 2;
        float wy = y - (float)y0, wx = x - (float)x0;
        int i00 = y0 * W_ + x0;
        float w00 = (1.0f - wy) * (1.0f - wx), w01 = (1.0f - wy) * wx;
        float w10 = wy * (1.0f - wx),          w11 = wy * wx;
        const float* dB0 = desc2 + ((size_t)b * C_ + l) * HW_;
        const float* dB1 = desc2 + ((size_t)b * C_ + l + 64) * HW_;
        float v0 = dB0[i00] * w00 + dB0[i00 + 1] * w01
                 + dB0[i00 + W_] * w10 + dB0[i00 + W_ + 1] * w11;
        float v1 = dB1[i00] * w00 + dB1[i00 + 1] * w01
                 + dB1[i00 + W_] * w10 + dB1[i00 + W_ + 1] * w11;
        float s = v0 * v0 + v1 * v1;
        s += __shfl_xor(s, 1);  s += __shfl_xor(s, 2);  s += __shfl_xor(s, 4);
        s += __shfl_xor(s, 8);  s += __shfl_xor(s, 16); s += __shfl_xor(s, 32);
        float inv = 1.0f / (sqrtf(s) + 1e-8f);
        float vn0 = v0 * inv, vn1 = v1 * inv;
        w_bf[(size_t)bn * C_ + l]      = (unsigned short)f2bf(vn0);
        w_bf[(size_t)bn * C_ + 64 + l] = (unsigned short)f2bf(vn1);
        float qd0 = kp1_desc[(size_t)bn * C_ + l];
        float qd1 = kp1_desc[(size_t)bn * C_ + 64 + l];
        float d = qd0 * vn0 + qd1 * vn1;
        d += __shfl_xor(d, 1);  d += __shfl_xor(d, 2);  d += __shfl_xor(d, 4);
        d += __shfl_xor(d, 8);  d += __shfl_xor(d, 16); d += __shfl_xor(d, 32);
        if (l == 0) pos[bn] = 2.0f - 2.0f * d;
    }
}

// ---------------------------------------------------------------------------
// KB fused: [0,256) k3a rowmax pass; [256,384) k4a psim pass.
// ---------------------------------------------------------------------------
__global__ __launch_bounds__(512) void hqt_kb(
    const unsigned short* __restrict__ q_bf,
    const unsigned short* __restrict__ w_bf,
    const unsigned short* __restrict__ d2t,
    const int* __restrict__ cid4, const int* __restrict__ wid4,
    const int* __restrict__ wcc16,
    float* __restrict__ rowmax, float* __restrict__ psim) {
    int blk = blockIdx.x;
    int tid = threadIdx.x, w = tid >> 6, l = tid & 63;
    int l15 = l & 15, lg = l >> 4;
    if (blk < 256) {
        int b = blk >> 7;
        int rg = (blk >> 4) & 7;
        int cb = blk & 15;
        int rowbase = rg * 64;
        int colbase = cb * 1024 + w * 128;
        const unsigned short* qb = q_bf + (size_t)b * N_ * C_;
        const unsigned short* db = d2t + (size_t)b * HW_ * C_;
        short8 a[4][4];
#pragma unroll
        for (int rt = 0; rt < 4; ++rt)
#pragma unroll
            for (int ks = 0; ks < 4; ++ks)
                a[rt][ks] = *(const short8*)(qb + (size_t)(rowbase + rt * 16 + l15) * C_ + ks * 32 + lg * 8);
        f32x4 mx[4];
#pragma unroll
        for (int rt = 0; rt < 4; ++rt) mx[rt] = f32x4{-1e30f, -1e30f, -1e30f, -1e30f};
#pragma unroll
        for (int t = 0; t < 8; ++t) {
            const unsigned short* dp = db + (size_t)(colbase + t * 16 + l15) * C_ + lg * 8;
            short8 b0 = *(const short8*)(dp);
            short8 b1 = *(const short8*)(dp + 32);
            short8 b2 = *(const short8*)(dp + 64);
            short8 b3 = *(const short8*)(dp + 96);
#pragma unroll
            for (int rt = 0; rt < 4; ++rt) {
                f32x4 acc4 = {0.0f, 0.0f, 0.0f, 0.0f};
                acc4 = __builtin_amdgcn_mfma_f32_16x16x32_bf16(a[rt][0], b0, acc4, 0, 0, 0);
                acc4 = __builtin_amdgcn_mfma_f32_16x16x32_bf16(a[rt][1], b1, acc4, 0, 0, 0);
                acc4 = __builtin_amdgcn_mfma_f32_16x16x32_bf16(a[rt][2], b2, acc4, 0, 0, 0);
                acc4 = __builtin_amdgcn_mfma_f32_16x16x32_bf16(a[rt][3], b3, acc4, 0, 0, 0);
#pragma unroll
                for (int r = 0; r < 4; ++r) mx[rt][r] = fmaxf(mx[rt][r], acc4[r]);
            }
        }
#pragma unroll
        for (int rt = 0; rt < 4; ++rt)
#pragma unroll
            for (int r = 0; r < 4; ++r) {
                float v = mx[rt][r];
                v = fmaxf(v, __shfl_xor(v, 1));
                v = fmaxf(v, __shfl_xor(v, 2));
                v = fmaxf(v, __shfl_xor(v, 4));
                v = fmaxf(v, __shfl_xor(v, 8));
                mx[rt][r] = v;
            }
        if (l15 == 0) {
            int chunk = cb * 8 + w;
#pragma unroll
            for (int rt = 0; rt < 4; ++rt)
#pragma unroll
                for (int r = 0; r < 4; ++r) {
                    int rowg = b * N_ + rowbase + rt * 16 + lg * 4 + r;
                    rowmax[(size_t)rowg * 128 + chunk] = mx[rt][r];
                }
        }
    } else {
        int blk2 = blk - 256;
        int mat = blk2 >> 6;
        int b = (blk2 >> 5) & 1;
        int r0 = (blk2 & 31) * 16;
        const unsigned short* src = (mat ? w_bf : q_bf) + (size_t)b * N_ * C_;

        __shared__ int s_colids[N_][4];
        __shared__ int s_rowcc[16][16];
        {
            const int4* gsrc = (const int4*)((mat ? wid4 : cid4) + b * N_ * 4);
            ((int4*)s_colids)[tid] = gsrc[tid];
            if (tid < 256)
                ((int*)s_rowcc)[tid] = wcc16[(b * N_ + r0) * 16 + tid];
        }
        short8 a0 = *(const short8*)(src + (size_t)(r0 + l15) * C_ + lg * 8);
        short8 a1 = *(const short8*)(src + (size_t)(r0 + l15) * C_ + 32 + lg * 8);
        short8 a2 = *(const short8*)(src + (size_t)(r0 + l15) * C_ + 64 + lg * 8);
        short8 a3 = *(const short8*)(src + (size_t)(r0 + l15) * C_ + 96 + lg * 8);
        __syncthreads();

        int4 rowc[4];
        int rcc[4][16];
#pragma unroll
        for (int r = 0; r < 4; ++r) {
            rowc[r] = *(const int4*)(&s_colids[r0 + lg * 4 + r][0]);
            if (mat == 1) {
#pragma unroll
                for (int i = 0; i < 16; ++i) rcc[r][i] = s_rowcc[lg * 4 + r][i];
            }
        }

        float* prow = psim + ((size_t)(mat * B_ + b) * N_) * N_;
#pragma unroll
        for (int t = 0; t < 4; ++t) {
            int col0 = w * 64 + t * 16;
            const unsigned short* dp = src + (size_t)(col0 + l15) * C_ + lg * 8;
            short8 b0 = *(const short8*)(dp);
            short8 b1 = *(const short8*)(dp + 32);
            short8 b2 = *(const short8*)(dp + 64);
            short8 b3 = *(const short8*)(dp + 96);
            f32x4 acc4 = {0.0f, 0.0f, 0.0f, 0.0f};
            acc4 = __builtin_amdgcn_mfma_f32_16x16x32_bf16(a0, b0, acc4, 0, 0, 0);
            acc4 = __builtin_amdgcn_mfma_f32_16x16x32_bf16(a1, b1, acc4, 0, 0, 0);
            acc4 = __builtin_amdgcn_mfma_f32_16x16x32_bf16(a2, b2, acc4, 0, 0, 0);
            acc4 = __builtin_amdgcn_mfma_f32_16x16x32_bf16(a3, b3, acc4, 0, 0, 0);
            int mycol = col0 + l15;
            int4 cc = *(const int4*)(&s_colids[mycol][0]);
#pragma unroll
            for (int r = 0; r < 4; ++r) {
                int cnt = 0;
                if (mat == 0) {
#pragma unroll
                    for (int j = 0; j < 4; ++j) {
                        int u = (j == 0) ? rowc[r].x : (j == 1) ? rowc[r].y
                              : (j == 2) ? rowc[r].z : rowc[r].w;
                        cnt += (u == cc.x) + (u == cc.y) + (u == cc.z) + (u == cc.w);
                    }
                } else {
#pragma unroll
                    for (int i = 0; i < 16; ++i) {
                        int u = rcc[r][i];
                        cnt += (u == cc.x) + (u == cc.y) + (u == cc.z) + (u == cc.w);
                    }
                }
                float key = acc4[r] - 2.5f * (float)cnt;
                prow[(size_t)(r0 + lg * 4 + r) * N_ + mycol] = key;
            }
        }
    }
}

// ---------------------------------------------------------------------------
// K3b: broadcast rank-scan. One wave per row; lane owns 2 of 128 window
// maxima; all lanes scan the same row from LDS (broadcast, conflict-free);
// the rank-31 lane writes t32[row].
// ---------------------------------------------------------------------------
__global__ __launch_bounds__(256) void hqt_k3b(
    const float* __restrict__ rowmax, float* __restrict__ t32) {
    int w = threadIdx.x >> 6, l = threadIdx.x & 63;
    int row = blockIdx.x * 4 + w;
    __shared__ float sm[4][128];
    const float* rm = rowmax + (size_t)row * 128;
    float c0 = rm[l];
    float c1 = rm[64 + l];
    sm[w][l] = c0;
    sm[w][64 + l] = c1;
    __syncthreads();
    int r0 = 0, r1 = 0;
    for (int j = 0; j < 128; j += 4) {
        float4 kk = *(const float4*)&sm[w][j];
#pragma unroll
        for (int e = 0; e < 4; ++e) {
            float key = (e == 0) ? kk.x : (e == 1) ? kk.y : (e == 2) ? kk.z : kk.w;
            int jj = j + e;
            r0 += (key > c0) || (key == c0 && jj < l);
            r1 += (key > c1) || (key == c1 && jj < 64 + l);
        }
    }
    if (r0 == 31) t32[row] = c0;
    if (r1 == 31) t32[row] = c1;
}

// ---------------------------------------------------------------------------
// KC: survivor pass (t32 from global).
// ---------------------------------------------------------------------------
__global__ __launch_bounds__(512) void hqt_kc(
    const unsigned short* __restrict__ q_bf,
    const unsigned short* __restrict__ d2t,
    const float* __restrict__ t32,
    int* __restrict__ scnt, float2* __restrict__ sbuf) {
    int blk = blockIdx.x;
    int b = blk >> 7;
    int rg = (blk >> 4) & 7;
    int cb = blk & 15;
    int tid = threadIdx.x, w = tid >> 6, l = tid & 63;
    int l15 = l & 15, lg = l >> 4;
    int rowbase = rg * 64;
    int colbase = cb * 1024 + w * 128;
    const unsigned short* qb = q_bf + (size_t)b * N_ * C_;
    const unsigned short* db = d2t + (size_t)b * HW_ * C_;
    short8 a[4][4];
#pragma unroll
    for (int rt = 0; rt < 4; ++rt)
#pragma unroll
        for (int ks = 0; ks < 4; ++ks)
            a[rt][ks] = *(const short8*)(qb + (size_t)(rowbase + rt * 16 + l15) * C_ + ks * 32 + lg * 8);
    float tl[4][4];
#pragma unroll
    for (int rt = 0; rt < 4; ++rt)
#pragma unroll
        for (int r = 0; r < 4; ++r)
            tl[rt][r] = t32[b * N_ + rowbase + rt * 16 + lg * 4 + r];
#pragma unroll
    for (int t = 0; t < 8; ++t) {
        const unsigned short* dp = db + (size_t)(colbase + t * 16 + l15) * C_ + lg * 8;
        short8 b0 = *(const short8*)(dp);
        short8 b1 = *(const short8*)(dp + 32);
        short8 b2 = *(const short8*)(dp + 64);
        short8 b3 = *(const short8*)(dp + 96);
#pragma unroll
        for (int rt = 0; rt < 4; ++rt) {
            f32x4 acc4 = {0.0f, 0.0f, 0.0f, 0.0f};
            acc4 = __builtin_amdgcn_mfma_f32_16x16x32_bf16(a[rt][0], b0, acc4, 0, 0, 0);
            acc4 = __builtin_amdgcn_mfma_f32_16x16x32_bf16(a[rt][1], b1, acc4, 0, 0, 0);
            acc4 = __builtin_amdgcn_mfma_f32_16x16x32_bf16(a[rt][2], b2, acc4, 0, 0, 0);
            acc4 = __builtin_amdgcn_mfma_f32_16x16x32_bf16(a[rt][3], b3, acc4, 0, 0, 0);
#pragma unroll
            for (int r = 0; r < 4; ++r) {
                float d = acc4[r];
                if (d >= tl[rt][r]) {
                    int rowg = b * N_ + rowbase + rt * 16 + lg * 4 + r;
                    int idx = atomicAdd(scnt + rowg, 1);
                    if (idx < SCAP_) {
                        float2 e;
                        e.x = d;
                        e.y = __int_as_float(colbase + t * 16 + l15);
                        sbuf[(size_t)rowg * SCAP_ + idx] = e;
                    }
                }
            }
        }
    }
}

// ---------------------------------------------------------------------------
// KD: [0,256) fos via rank-scan top-16; [256,512) sos via rank-scan top-8.
// Atomic-ticket finalize.
// ---------------------------------------------------------------------------
__global__ __launch_bounds__(256) void hqt_kd(
    const unsigned short* __restrict__ q_bf,
    const unsigned short* __restrict__ d2t,
    const unsigned int* __restrict__ marked,
    const int* __restrict__ scnt, const float2* __restrict__ sbuf,
    const float* __restrict__ pos, const float* __restrict__ psim,
    const int* __restrict__ cid4, const int* __restrict__ wid4,
    const int* __restrict__ wcc16, float* __restrict__ acc,
    float* __restrict__ out) {
    int blk = blockIdx.x;
    int w = threadIdx.x >> 6, l = threadIdx.x & 63;
    if (blk < 256) {
        // ================= fos: exact penalized top-16 via rank-scan ======
        __shared__ float keys[4][160];
        int row = blk * 4 + w;
        int b = row >> 9;
        int sc = scnt[row]; if (sc > SCAP_) sc = SCAP_;
        float k0 = -1e30f, k1 = -1e30f;
        int c0 = -1, c1 = -1;
        if (l < sc) {
            float2 e = sbuf[(size_t)row * SCAP_ + l];
            k0 = e.x; c0 = __float_as_int(e.y);
        }
        if (64 + l < sc) {
            float2 e = sbuf[(size_t)row * SCAP_ + 64 + l];
            k1 = e.x; c1 = __float_as_int(e.y);
        }
#pragma unroll
        for (int i = 0; i < 16; ++i) {
            unsigned int mv = marked[row * 16 + i];
            int id = (int)(mv & 0xFFFFu);
            if (c0 == id) k0 = -1e30f;
            if (c1 == id) k1 = -1e30f;
        }
        // marked keys (exact, 4 lanes per marked slot)
        float k2c = -1e30f;
        int mi = l >> 2;
        {
            int cq = l & 3;
            unsigned int mv = marked[row * 16 + mi];
            bool valid = (mv != 0xFFFFFFFFu);
            int col = valid ? (int)(mv & 0xFFFFu) : 0;
            int cnt = (int)(mv >> 16);
            const unsigned short* qp = q_bf + (size_t)row * C_ + cq * 32;
            const unsigned short* dp = d2t + ((size_t)b * HW_ + col) * C_ + cq * 32;
            float dot = 0.0f;
#pragma unroll
            for (int u = 0; u < 4; ++u) {
                short8 qv = *(const short8*)(qp + u * 8);
                short8 dv = *(const short8*)(dp + u * 8);
#pragma unroll
                for (int e = 0; e < 8; ++e)
                    dot = fmaf(bf2f((unsigned short)qv[e]), bf2f((unsigned short)dv[e]), dot);
            }
            dot += __shfl_xor(dot, 1);
            dot += __shfl_xor(dot, 2);
            k2c = valid ? (dot - 2.5f * (float)cnt) : -1e30f;
            // stage keys
            keys[w][l] = k0;
            keys[w][64 + l] = k1;
            if (cq == 0) keys[w][128 + mi] = k2c;
            if (l < 16) keys[w][144 + l] = -1e30f;   // pad
        }
        __syncthreads();
        // rank-scan: candidates (k0@l), (k1@64+l), (k2c@128+l for l<16)
        float cC = (l < 16) ? keys[w][128 + l] : -1e30f;
        int idxC = 128 + l;
        int r0 = 0, r1 = 0, r2 = 0;
        for (int j = 0; j < 144; j += 4) {
            float4 kk = *(const float4*)&keys[w][j];
#pragma unroll
            for (int e = 0; e < 4; ++e) {
                float key = (e == 0) ? kk.x : (e == 1) ? kk.y : (e == 2) ? kk.z : kk.w;
                int jj = j + e;
                r0 += (key > k0) || (key == k0 && jj < l);
                r1 += (key > k1) || (key == k1 && jj < 64 + l);
                r2 += (key > cC) || (key == cC && jj < idxC);
            }
        }
        float pos_r = pos[row];
        float sum = 0.0f;
        if (r0 < 16) { float h = fmaxf(pos_r + 2.0f * k0 - 1.0f, 0.0f); sum += h * h; }
        if (r1 < 16) { float h = fmaxf(pos_r + 2.0f * k1 - 1.0f, 0.0f); sum += h * h; }
        if (r2 < 16) { float h = fmaxf(pos_r + 2.0f * cC - 1.0f, 0.0f); sum += h * h; }
        sum += __shfl_xor(sum, 1);  sum += __shfl_xor(sum, 2);
        sum += __shfl_xor(sum, 4);  sum += __shfl_xor(sum, 8);
        sum += __shfl_xor(sum, 16); sum += __shfl_xor(sum, 32);
        if (l == 0) atomicAdd(acc + 0, sum);
    } else {
        // ================= sos: rank-scan top-8 per (row, mat) ============
        __shared__ float cand[4][128];
        __shared__ float sval[4][64];
        __shared__ int   scol[4][64];
        __shared__ int   cnt_l[4];
        __shared__ float tpp[4];
        __shared__ float sel[4][2][8];
        int rowg = (blk - 256) * 4 + w;
        int b = rowg >> 9;
        int row = rowg & 511;
#pragma unroll 1
        for (int mat = 0; mat < 2; ++mat) {
            const float* pr = psim + ((size_t)(mat * B_ + b) * N_ + row) * N_;
            float4 u0 = ((const float4*)pr)[l * 2];
            float4 u1 = ((const float4*)pr)[l * 2 + 1];
            float k[8] = {u0.x, u0.y, u0.z, u0.w, u1.x, u1.y, u1.z, u1.w};
            // per-lane top-2 (values only)
            float m1 = -1e30f, m2 = -1e30f;
#pragma unroll
            for (int i = 0; i < 8; ++i) {
                float v = k[i];
                bool g1 = v > m1;
                m2 = g1 ? m1 : fmaxf(m2, v);
                m1 = g1 ? v : m1;
            }
            if (l == 0) cnt_l[w] = 0;
            cand[w][l] = m1;
            cand[w][64 + l] = m2;
            __syncthreads();
            // t8' = 8th largest of the 128-set (strict by value, then slot)
            int rA = 0, rB = 0;
            for (int j = 0; j < 128; j += 4) {
                float4 cc = *(const float4*)&cand[w][j];
#pragma unroll
                for (int e = 0; e < 4; ++e) {
                    float cv = (e == 0) ? cc.x : (e == 1) ? cc.y : (e == 2) ? cc.z : cc.w;
                    int jj = j + e;
                    rA += (cv > m1) || (cv == m1 && jj < l);
                    rB += (cv > m2) || (cv == m2 && jj < 64 + l);
                }
            }
            if (rA == 7) tpp[w] = m1;
            if (rB == 7) tpp[w] = m2;
            __syncthreads();
            float t8 = tpp[w];
            // survivors (v >= t8 by value) -> LDS via atomic ticket
#pragma unroll
            for (int i = 0; i < 8; ++i) {
                if (k[i] >= t8) {
                    int s = atomicAdd(&cnt_l[w], 1);
                    if (s < 64) { sval[w][s] = k[i]; scol[w][s] = l * 8 + i; }
                }
            }
            __syncthreads();
            int cnt = cnt_l[w]; if (cnt > 64) cnt = 64;
            // rank survivors: (value desc, col asc) == lax.top_k order
            float sv = (l < cnt) ? sval[w][l] : -1e30f;
            int   scm = (l < cnt) ? scol[w][l] : INT_MAX;
            int r = 0;
            for (int j = 0; j < cnt; ++j) {
                float vj = sval[w][j];
                int cj = scol[w][j];
                r += (vj > sv) || (vj == sv && cj < scm);
            }
            if (l < cnt && r < 8) {
                // reconstruct clean dot: key + 2.5 * exact mask count
                int cntm = 0;
                if (mat == 0) {
                    const int4* cb4 = (const int4*)(cid4 + b * N_ * 4);
                    int4 rc = cb4[row];
                    int4 mc = cb4[scm];
#pragma unroll
                    for (int j = 0; j < 4; ++j) {
                        int u = (j == 0) ? rc.x : (j == 1) ? rc.y : (j == 2) ? rc.z : rc.w;
                        cntm += (u == mc.x) + (u == mc.y) + (u == mc.z) + (u == mc.w);
                    }
                } else {
                    const int4* wb4 = (const int4*)(wid4 + b * N_ * 4);
                    int4 mw = wb4[scm];
                    const int4* rcc = (const int4*)(wcc16 + (b * N_ + row) * 16);
#pragma unroll
                    for (int uq = 0; uq < 4; ++uq) {
                        int4 rr = rcc[uq];
                        cntm += (rr.x == mw.x) + (rr.x == mw.y) + (rr.x == mw.z) + (rr.x == mw.w);
                        cntm += (rr.y == mw.x) + (rr.y == mw.y) + (rr.y == mw.z) + (rr.y == mw.w);
                        cntm += (rr.z == mw.x) + (rr.z == mw.y) + (rr.z == mw.z) + (rr.z == mw.w);
                        cntm += (rr.w == mw.x) + (rr.w == mw.y) + (rr.w == mw.z) + (rr.w == mw.w);
                    }
                }
                sel[w][mat][r] = sv + 2.5f * (float)cntm;
            }
            __syncthreads();
        }
        if (l < 8) {
            float t2 = 2.0f * (sel[w][1][l] - sel[w][0][l]);
            float sq = t2 * t2;
            sq += __shfl_xor(sq, 1);
            sq += __shfl_xor(sq, 2);
            sq += __shfl_xor(sq, 4);
            if (l == 0) atomicAdd(acc + 1, sqrtf(sq));
        }
    }
    // ---- ticket finalize ----
    __syncthreads();
    if (threadIdx.x == 0) {
        __threadfence();
        unsigned int t = atomicAdd((unsigned int*)(acc + 2), 1u);
        if (t == 511u) {
            float a0 = atomicAdd(acc + 0, 0.0f);
            float a1 = atomicAdd(acc + 1, 0.0f);
            out[0] = a0 * (1.0f / (float)(B_ * N_ * NUM_NEG_))
                   + a1 * (1.0f / (float)(B_ * N_));
        }
    }
}

// ======================= fallback (round-1) kernels ========================
__global__ void hqt_k1_cells(const float* __restrict__ kp1,
                             const float* __restrict__ w_kp1,
                             const float* __restrict__ homo,
                             int* __restrict__ cid4,
                             int* __restrict__ wcc16,
                             int* __restrict__ wid4) {
    int t = blockIdx.x * blockDim.x + threadIdx.x;
    if (t >= B_ * N_) return;
    int b = t / N_;
    float ky = kp1[2 * t], kx = kp1[2 * t + 1];
    int ids[4];
    nearest4(ky, kx, ids);
    const float* Hb = homo + 9 * b;
    float h00 = Hb[0], h01 = Hb[1], h02 = Hb[2];
    float h10 = Hb[3], h11 = Hb[4], h12 = Hb[5];
    float h20 = Hb[6], h21 = Hb[7], h22 = Hb[8];
#pragma unroll
    for (int i = 0; i < 4; ++i) {
        int id = ids[i];
        cid4[4 * t + i] = id;
        float cy = 8.0f * (id >> 7) + 4.0f;
        float cx = 8.0f * (id & 127) + 4.0f;
        float X = cx, Y = cy;
        float wz = h20 * X + h21 * Y + h22;
        float inv = 1.0f / (wz + 1e-8f);
        float wy = (h10 * X + h11 * Y + h12) * inv;
        float wx = (h00 * X + h01 * Y + h02) * inv;
        int wids[4];
        nearest4(wy, wx, wids);
#pragma unroll
        for (int j = 0; j < 4; ++j) wcc16[16 * t + 4 * i + j] = wids[j];
    }
    float zy = w_kp1[2 * t], zx = w_kp1[2 * t + 1];
    int wi4[4];
    nearest4(zy, zx, wi4);
#pragma unroll
    for (int j = 0; j < 4; ++j) wid4[4 * t + j] = wi4[j];
}

__global__ __launch_bounds__(128) void hqt_k2_sample_f32(
    const float* __restrict__ w_kp1, const float* __restrict__ desc2,
    const float* __restrict__ kp1_desc, float* __restrict__ w_desc,
    float* __restrict__ pos) {
    int bn = blockIdx.x;
    int b = bn / N_;
    int c = threadIdx.x;
    float ky = w_kp1[2 * bn], kx = w_kp1[2 * bn + 1];
    float y = fminf(fmaxf(ky * 0.125f - 0.5f, 0.0f), (float)(H_ - 1));
    float x = fminf(fmaxf(kx * 0.125f - 0.5f, 0.0f), (float)(W_ - 1));
    int y0 = (int)floorf(y); if (y0 > H_ - 2) y0 = H_ - 2;
    int x0 = (int)floorf(x); if (x0 > W_ - 2) x0 = W_ - 2;
    float wy = y - (float)y0, wx = x - (float)x0;
    const float* dB = desc2 + ((size_t)b * C_ + c) * HW_;
    int i00 = y0 * W_ + x0;
    float v = dB[i00]          * (1.0f - wy) * (1.0f - wx)
            + dB[i00 + 1]      * (1.0f - wy) * wx
            + dB[i00 + W_]     * wy * (1.0f - wx)
            + dB[i00 + W_ + 1] * wy * wx;
    __shared__ float red[128];
    red[c] = v * v;
    __syncthreads();
    for (int s = 64; s > 0; s >>= 1) {
        if (c < s) red[c] += red[c + s];
        __syncthreads();
    }
    float nrm = sqrtf(red[0]);
    __syncthreads();
    float vn = v / (nrm + 1e-8f);
    w_desc[(size_t)bn * C_ + c] = vn;
    float qd = kp1_desc[(size_t)bn * C_ + c];
    red[c] = qd * vn;
    __syncthreads();
    for (int s = 64; s > 0; s >>= 1) {
        if (c < s) red[c] += red[c + s];
        __syncthreads();
    }
    if (c == 0) pos[bn] = 2.0f - 2.0f * red[0];
}

__device__ inline void insert8_vi(float (&av)[8], int (&ai)[8], float v, int id) {
    bool le = (v < av[7]) || (v == av[7] && id < ai[7]);
    if (!le) return;
#pragma unroll
    for (int k = 0; k < 8; ++k) {
        float ov = av[k]; int oi = ai[k];
        bool sm = (v < ov) || (v == ov && id < oi);
        av[k] = sm ? v : ov;  ai[k] = sm ? id : oi;
        v = sm ? ov : v;      id = sm ? oi : id;
    }
}

__device__ inline void bitonic8_pairs(float (&av)[8], int (&ai)[8]) {
#pragma unroll
    for (int dd = 0; dd < 3; ++dd) {
        const int d = 4 >> dd;
#pragma unroll
        for (int i = 0; i < 8; ++i) {
            if ((i & d) == 0) {
                bool sw = (av[i + d] < av[i]) ||
                          (av[i + d] == av[i] && ai[i + d] < ai[i]);
                float tv = av[i]; int ti = ai[i];
                av[i]     = sw ? av[i + d] : av[i];
                ai[i]     = sw ? ai[i + d] : ai[i];
                av[i + d] = sw ? tv : av[i + d];
                ai[i + d] = sw ? ti : ai[i + d];
            }
        }
    }
}

__device__ inline void bitonic16_asc(float (&a)[16]) {
#pragma unroll
    for (int dd = 0; dd < 4; ++dd) {
        const int d = 8 >> dd;
#pragma unroll
        for (int i = 0; i < 16; ++i) {
            if ((i & d) == 0) {
                float lo = fminf(a[i], a[i + d]);
                float hi = fmaxf(a[i], a[i + d]);
                a[i] = lo; a[i + d] = hi;
            }
        }
    }
}

#define T3 512
#define R3 4
__global__ __launch_bounds__(T3) void hqt_k3_dsim(
    const float* __restrict__ desc2, const float* __restrict__ kp1_desc,
    const int* __restrict__ wcc16, const float* __restrict__ pos,
    float* __restrict__ acc) {
    const int nb = N_ / R3;
    int b = blockIdx.x / nb;
    int n0 = (blockIdx.x % nb) * R3;
    int tid = threadIdx.x;
    __shared__ float qT[C_][R3];
    __shared__ int ids_s[R3][16];
    {
        int r = tid & 3, c = tid >> 2;
        qT[c][r] = kp1_desc[(size_t)(b * N_ + n0 + r) * C_ + c];
    }
    if (tid < R3 * 16)
        ids_s[tid >> 4][tid & 15] = wcc16[(b * N_ + n0) * 16 + tid];
    __syncthreads();

    float top[R3][16];
#pragma unroll
    for (int r = 0; r < R3; ++r)
#pragma unroll
        for (int k = 0; k < 16; ++k) top[r][k] = 1e30f;

    const float* d2b = desc2 + (size_t)b * C_ * HW_;
#pragma unroll 1
    for (int g = 0; g < HW_ / (T3 * 4); ++g) {
        int j0 = (g * T3 + tid) * 4;
        float4 A0 = {0, 0, 0, 0}, A1 = {0, 0, 0, 0}, A2 = {0, 0, 0, 0}, A3 = {0, 0, 0, 0};
        for (int c = 0; c < C_; ++c) {
            float4 d = *reinterpret_cast<const float4*>(d2b + (size_t)c * HW_ + j0);
            float4 qv = *reinterpret_cast<const float4*>(&qT[c][0]);
            A0.x = fmaf(qv.x, d.x, A0.x); A0.y = fmaf(qv.x, d.y, A0.y);
            A0.z = fmaf(qv.x, d.z, A0.z); A0.w = fmaf(qv.x, d.w, A0.w);
            A1.x = fmaf(qv.y, d.x, A1.x); A1.y = fmaf(qv.y, d.y, A1.y);
            A1.z = fmaf(qv.y, d.z, A1.z); A1.w = fmaf(qv.y, d.w, A1.w);
            A2.x = fmaf(qv.z, d.x, A2.x); A2.y = fmaf(qv.z, d.y, A2.y);
            A2.z = fmaf(qv.z, d.z, A2.z); A2.w = fmaf(qv.z, d.w, A2.w);
            A3.x = fmaf(qv.w, d.x, A3.x); A3.y = fmaf(qv.w, d.y, A3.y);
            A3.z = fmaf(qv.w, d.z, A3.z); A3.w = fmaf(qv.w, d.w, A3.w);
        }
#pragma unroll
        for (int r = 0; r < R3; ++r) {
            float dots[4];
            dots[0] = (r == 0) ? A0.x : (r == 1) ? A1.x : (r == 2) ? A2.x : A3.x;
            dots[1] = (r == 0) ? A0.y : (r == 1) ? A1.y : (r == 2) ? A2.y : A3.y;
            dots[2] = (r == 0) ? A0.z : (r == 1) ? A1.z : (r == 2) ? A2.z : A3.z;
            dots[3] = (r == 0) ? A0.w : (r == 1) ? A1.w : (r == 2) ? A2.w : A3.w;
#pragma unroll
        for (int cc = 0; cc < 4; ++cc) {
                int j = j0 + cc;
                int cnt = 0;
#pragma unroll
                for (int i = 0; i < 16; ++i) cnt += (ids_s[r][i] == j) ? 1 : 0;
                float v = 2.0f - 2.0f * dots[cc] + 5.0f * (float)cnt;
                if (v < top[r][15]) {
#pragma unroll
                    for (int k = 0; k < 16; ++k) {
                        float o = top[r][k];
                        bool sm = v < o;
                        top[r][k] = sm ? v : o;
                        v = sm ? o : v;
                    }
                }
            }
        }
    }

    __shared__ float mv[T3][17];
#pragma unroll
    for (int r = 0; r < R3; ++r) {
        float a[16];
#pragma unroll
        for (int k = 0; k < 16; ++k) { a[k] = top[r][k]; mv[tid][k] = a[k]; }
        __syncthreads();
        for (int step = T3 / 2; step >= 1; step >>= 1) {
            if (tid < step) {
#pragma unroll
                for (int i = 0; i < 16; ++i)
                    a[i] = fminf(a[i], mv[tid + step][15 - i]);
                bitonic16_asc(a);
#pragma unroll
                for (int i = 0; i < 16; ++i) mv[tid][i] = a[i];
            }
            __syncthreads();
        }
        if (tid == 0) {
            float p = pos[b * N_ + n0 + r];
            float s = 0.0f;
#pragma unroll
            for (int k = 0; k < 16; ++k) {
                float xv = p - a[k] + 1.0f;
                xv = fmaxf(xv, 0.0f);
                s += xv * xv;
            }
            atomicAdd(acc + 0, s);
        }
        __syncthreads();
    }
}

__global__ __launch_bounds__(64) void hqt_k4_sos(
    const float* __restrict__ kp1_desc, const float* __restrict__ w_desc,
    const int* __restrict__ cid4, const int* __restrict__ wcc16,
    const int* __restrict__ wid4, float* __restrict__ acc) {
    int bn = blockIdx.x;
    int b = bn / N_;
    int lane = threadIdx.x;
    __shared__ float qk[C_], qw[C_];
    for (int c = lane; c < C_; c += 64) {
        qk[c] = kp1_desc[(size_t)bn * C_ + c];
        qw[c] = w_desc[(size_t)bn * C_ + c];
    }
    __syncthreads();
    int nk[4];
#pragma unroll
    for (int i = 0; i < 4; ++i) nk[i] = cid4[4 * bn + i];
    int nw[16];
#pragma unroll
    for (int i = 0; i < 16; ++i) nw[i] = wcc16[16 * bn + i];

    float kv[8], wv[8]; int ki[8], wi[8];
#pragma unroll
    for (int k = 0; k < 8; ++k) {
        kv[k] = 1e30f; wv[k] = 1e30f; ki[k] = INT_MAX; wi[k] = INT_MAX;
    }
    const float* kb = kp1_desc + (size_t)b * N_ * C_;
    const float* wb = w_desc + (size_t)b * N_ * C_;
    for (int tt = 0; tt < 8; ++tt) {
        int m = lane * 8 + tt;
        const float* rk = kb + (size_t)m * C_;
        const float* rw = wb + (size_t)m * C_;
        float dk = 0.0f, dw = 0.0f;
        for (int c = 0; c < C_; c += 4) {
            float4 xk = *(const float4*)(rk + c);
            float4 xw = *(const float4*)(rw + c);
            dk += qk[c] * xk.x + qk[c + 1] * xk.y + qk[c + 2] * xk.z + qk[c + 3] * xk.w;
            dw += qw[c] * xw.x + qw[c + 1] * xw.y + qw[c + 2] * xw.z + qw[c + 3] * xw.w;
        }
        int4 mc = *(const int4*)(cid4 + 4 * (b * N_ + m));
        int ck = 0;
#pragma unroll
        for (int i = 0; i < 4; ++i) {
            int u = nk[i];
            ck += (u == mc.x) + (u == mc.y) + (u == mc.z) + (u == mc.w);
        }
        int4 mw = *(const int4*)(wid4 + 4 * (b * N_ + m));
        int cw = 0;
#pragma unroll
        for (int i = 0; i < 16; ++i) {
            int u = nw[i];
            cw += (u == mw.x) + (u == mw.y) + (u == mw.z) + (u == mw.w);
        }
        float vk = 2.0f - 2.0f * dk + 5.0f * (float)ck;
        float vw2 = 2.0f - 2.0f * dw + 5.0f * (float)cw;
        insert8_vi(kv, ki, vk, m);
        insert8_vi(wv, wi, vw2, m);
    }

    __shared__ float mvs[64][9];
    __shared__ int mis[64][9];
    __shared__ int fk[8], fw[8];

#pragma unroll
    for (int i = 0; i < 8; ++i) { mvs[lane][i] = kv[i]; mis[lane][i] = ki[i]; }
    __syncthreads();
    for (int step = 32; step >= 1; step >>= 1) {
        if (lane < step) {
            float bv[8]; int bix[8];
#pragma unroll
            for (int i = 0; i < 8; ++i) {
                bv[i] = mvs[lane + step][7 - i];
                bix[i] = mis[lane + step][7 - i];
            }
#pragma unroll
            for (int i = 0; i < 8; ++i) {
                bool ta = (kv[i] < bv[i]) || (kv[i] == bv[i] && ki[i] < bix[i]);
                kv[i] = ta ? kv[i] : bv[i];
                ki[i] = ta ? ki[i] : bix[i];
            }
            bitonic8_pairs(kv, ki);
#pragma unroll
            for (int i = 0; i < 8; ++i) { mvs[lane][i] = kv[i]; mis[lane][i] = ki[i]; }
        }
        __syncthreads();
    }
    if (lane < 8) fk[lane] = mis[0][lane];
    __syncthreads();

#pragma unroll
    for (int i = 0; i < 8; ++i) { mvs[lane][i] = wv[i]; mis[lane][i] = wi[i]; }
    __syncthreads();
    for (int step = 32; step >= 1; step >>= 1) {
        if (lane < step) {
            float bv[8]; int bix[8];
#pragma unroll
            for (int i = 0; i < 8; ++i) {
                bv[i] = mvs[lane + step][7 - i];
                bix[i] = mis[lane + step][7 - i];
            }
#pragma unroll
            for (int i = 0; i < 8; ++i) {
                bool ta = (wv[i] < bv[i]) || (wv[i] == bv[i] && wi[i] < bix[i]);
                wv[i] = ta ? wv[i] : bv[i];
                wi[i] = ta ? wi[i] : bix[i];
            }
            bitonic8_pairs(wv, wi);
#pragma unroll
            for (int i = 0; i < 8; ++i) { mvs[lane][i] = wv[i]; mis[lane][i] = wi[i]; }
        }
        __syncthreads();
    }
    if (lane < 8) fw[lane] = mis[0][lane];
    __syncthreads();

    int s = lane >> 3, p = lane & 7;
    const float* rk = kb + (size_t)fk[s] * C_;
    const float* rw = wb + (size_t)fw[s] * C_;
    float dk = 0.0f, dw = 0.0f;
    for (int c = p; c < C_; c += 8) {
        dk += qk[c] * rk[c];
        dw += qw[c] * rw[c];
    }
    dk += __shfl_xor(dk, 1); dk += __shfl_xor(dk, 2); dk += __shfl_xor(dk, 4);
    dw += __shfl_xor(dw, 1); dw += __shfl_xor(dw, 2); dw += __shfl_xor(dw, 4);
    __shared__ float tsq[8];
    if (p == 0) {
        float t2 = 2.0f * (dw - dk);
        tsq[s] = t2 * t2;
    }
    __syncthreads();
    if (lane == 0) {
        float s8 = 0.0f;
#pragma unroll
        for (int i = 0; i < 8; ++i) s8 += tsq[i];
        atomicAdd(acc + 1, sqrtf(s8));
    }
}

__global__ void hqt_k5_final(const float* __restrict__ acc, float* __restrict__ out) {
    if (threadIdx.x == 0 && blockIdx.x == 0) {
        out[0] = acc[0] * (1.0f / (float)(B_ * N_ * NUM_NEG_))
               + acc[1] * (1.0f / (float)(B_ * N_));
    }
}

// ===========================================================================
extern "C" void kernel_launch(void* const* d_in, const int* in_sizes, int n_in,
                              void* d_out, int out_size, void* d_ws, size_t ws_size,
                              hipStream_t stream) {
    const float* kp1      = (const float*)d_in[0];
    const float* w_kp1    = (const float*)d_in[1];
    const float* kp1_desc = (const float*)d_in[2];
    const float* desc2    = (const float*)d_in[3];
    const float* homo     = (const float*)d_in[4];
    float* out = (float*)d_out;

    char* p = (char*)d_ws;
    auto alloc = [&](size_t bytes) {
        char* r = p;
        p += (bytes + 255) & ~(size_t)255;
        return r;
    };
    float*          pos    = (float*)alloc((size_t)B_ * N_ * 4);
    int*            cid4   = (int*)alloc((size_t)B_ * N_ * 4 * 4);
    int*            wid4   = (int*)alloc((size_t)B_ * N_ * 4 * 4);
    int*            wcc16  = (int*)alloc((size_t)B_ * N_ * 16 * 4);
    unsigned int*   marked = (unsigned int*)alloc((size_t)B_ * N_ * 16 * 4);
    float*          acc    = (float*)alloc(64);
    unsigned short* q_bf   = (unsigned short*)alloc((size_t)B_ * N_ * C_ * 2);
    unsigned short* w_bf   = (unsigned short*)alloc((size_t)B_ * N_ * C_ * 2);
    unsigned short* d2t    = (unsigned short*)alloc((size_t)B_ * HW_ * C_ * 2);
    float*          psim   = (float*)alloc((size_t)2 * B_ * N_ * N_ * 4);
    float*          rowmax = (float*)alloc((size_t)B_ * N_ * 128 * 4);
    float*          t32    = (float*)alloc((size_t)B_ * N_ * 4);
    int*            scnt   = (int*)alloc((size_t)B_ * N_ * 4);
    float2*         sbuf   = (float2*)alloc((size_t)B_ * N_ * SCAP_ * 8);
    size_t need = (size_t)(p - (char*)d_ws);

    if (ws_size >= need) {
        hqt_ka<<<1413, 256, 0, stream>>>(desc2, kp1_desc, kp1, w_kp1, homo,
                                         d2t, q_bf, w_bf, pos, cid4, wcc16,
                                         wid4, marked, scnt, acc);
        hqt_kb<<<384, 512, 0, stream>>>(q_bf, w_bf, d2t, cid4, wid4, wcc16,
                                        rowmax, psim);
        hqt_k3b<<<256, 256, 0, stream>>>(rowmax, t32);
        hqt_kc<<<256, 512, 0, stream>>>(q_bf, d2t, t32, scnt, sbuf);
        hqt_kd<<<512, 256, 0, stream>>>(q_bf, d2t, marked, scnt, sbuf, pos,
                                        psim, cid4, wid4, wcc16, acc, out);
    } else {
        // fallback: round-1 layout and path
        float* w_desc0 = (float*)d_ws;
        float* pos0    = w_desc0 + (size_t)B_ * N_ * C_;
        int*   cid40   = (int*)(pos0 + B_ * N_);
        int*   wid40   = cid40 + B_ * N_ * 4;
        int*   wcc160  = wid40 + B_ * N_ * 4;
        float* acc0    = (float*)(wcc160 + B_ * N_ * 16);
        hipMemsetAsync(acc0, 0, 2 * sizeof(float), stream);
        hqt_k1_cells<<<(B_ * N_ + 255) / 256, 256, 0, stream>>>(
            kp1, w_kp1, homo, cid40, wcc160, wid40);
        hqt_k2_sample_f32<<<B_ * N_, 128, 0, stream>>>(w_kp1, desc2, kp1_desc,
                                                       w_desc0, pos0);
        hqt_k3_dsim<<<B_ * (N_ / R3), T3, 0, stream>>>(desc2, kp1_desc, wcc160,
                                                       pos0, acc0);
        hqt_k4_sos<<<B_ * N_, 64, 0, stream>>>(kp1_desc, w_desc0, cid40,
                                               wcc160, wid40, acc0);
        hqt_k5_final<<<1, 1, 0, stream>>>(acc0, out);
    }
}

// Round 9
// 124.202 us; speedup vs baseline: 1.6754x; 1.0813x over previous
//
#include <hip/hip_runtime.h>
#include <climits>

#define B_ 2
#define N_ 512
#define C_ 128
#define H_ 128
#define W_ 128
#define HW_ (H_ * W_)
#define NUM_NEG_ 16
#define SOS_NEG_ 8
#define SCAP_ 128   // survivor cap per row

typedef __attribute__((ext_vector_type(8))) short short8;
typedef __attribute__((ext_vector_type(4))) float f32x4;

__device__ inline unsigned int f2bf(float x) {
    unsigned int u = __float_as_uint(x);
    return (u + 0x7FFFu + ((u >> 16) & 1u)) >> 16;
}
__device__ inline float bf2f(unsigned int h) {
    return __uint_as_float(h << 16);
}

// ---------------------------------------------------------------------------
// 4 nearest grid-cell centers of point (y,x); tie-break matches lax.top_k.
// ---------------------------------------------------------------------------
__device__ inline void nearest4(float y, float x, int out[4]) {
    y = fminf(fmaxf(y, -1e6f), 1e6f);
    x = fminf(fmaxf(x, -1e6f), 1e6f);
    int fy = (int)floorf(y * 0.125f - 0.5f);
    int fx = (int)floorf(x * 0.125f - 0.5f);
    int ylo = fy - 1; if (ylo < 0) ylo = 0; if (ylo > H_ - 4) ylo = H_ - 4;
    int xlo = fx - 1; if (xlo < 0) xlo = 0; if (xlo > W_ - 4) xlo = W_ - 4;
    float bd[4] = {1e30f, 1e30f, 1e30f, 1e30f};
    int   bi[4] = {INT_MAX, INT_MAX, INT_MAX, INT_MAX};
#pragma unroll
    for (int dyi = 0; dyi < 4; ++dyi) {
        int yi = ylo + dyi;
        float dy = y - (8.0f * yi + 4.0f);
        float dy2 = dy * dy;
#pragma unroll
        for (int dxi = 0; dxi < 4; ++dxi) {
            int xi = xlo + dxi;
            float dx = x - (8.0f * xi + 4.0f);
            float d = dy2 + dx * dx;
            int id = yi * W_ + xi;
#pragma unroll
            for (int k = 0; k < 4; ++k) {
                bool sm = (d < bd[k]) || (d == bd[k] && id < bi[k]);
                float od = bd[k]; int oi = bi[k];
                bd[k] = sm ? d : od;  bi[k] = sm ? id : oi;
                d = sm ? od : d;      id = sm ? oi : id;
            }
        }
    }
    out[0] = bi[0]; out[1] = bi[1]; out[2] = bi[2]; out[3] = bi[3];
}

__device__ inline void k1_body(int t, const float* kp1, const float* w_kp1,
                               const float* homo, int* cid4, int* wcc16,
                               int* wid4, unsigned int* marked) {
    int b = t / N_;
    float ky = kp1[2 * t], kx = kp1[2 * t + 1];
    int ids[4];
    nearest4(ky, kx, ids);
    const float* Hb = homo + 9 * b;
    float h00 = Hb[0], h01 = Hb[1], h02 = Hb[2];
    float h10 = Hb[3], h11 = Hb[4], h12 = Hb[5];
    float h20 = Hb[6], h21 = Hb[7], h22 = Hb[8];
    int w16[16];
#pragma unroll
    for (int i = 0; i < 4; ++i) {
        int id = ids[i];
        cid4[4 * t + i] = id;
        float cy = 8.0f * (id >> 7) + 4.0f;
        float cx = 8.0f * (id & 127) + 4.0f;
        float X = cx, Y = cy;
        float wz = h20 * X + h21 * Y + h22;
        float inv = 1.0f / (wz + 1e-8f);
        float wy = (h10 * X + h11 * Y + h12) * inv;
        float wx = (h00 * X + h01 * Y + h02) * inv;
        int wids[4];
        nearest4(wy, wx, wids);
#pragma unroll
        for (int j = 0; j < 4; ++j) {
            w16[4 * i + j] = wids[j];
            wcc16[16 * t + 4 * i + j] = wids[j];
        }
    }
#pragma unroll
    for (int i = 0; i < 16; ++i) {
        int cnt = 0; bool first = true;
#pragma unroll
        for (int j = 0; j < 16; ++j) {
            bool eq = (w16[j] == w16[i]);
            cnt += eq ? 1 : 0;
            if (j < i && eq) first = false;
        }
        marked[16 * t + i] = first ? ((unsigned int)w16[i] | ((unsigned int)cnt << 16))
                                   : 0xFFFFFFFFu;
    }
    float zy = w_kp1[2 * t], zx = w_kp1[2 * t + 1];
    int wi4[4];
    nearest4(zy, zx, wi4);
#pragma unroll
    for (int j = 0; j < 4; ++j) wid4[4 * t + j] = wi4[j];
}

// ---------------------------------------------------------------------------
// KA fused: [0,1024) d2t transpose; [1024,1152) q_bf; 1152 zero scnt/acc;
// [1153,1157) k1; [1157,1413) k2 (wave-per-keypoint, shfl-only).
// ---------------------------------------------------------------------------
__global__ __launch_bounds__(256) void hqt_ka(
    const float* __restrict__ desc2, const float* __restrict__ kp1_desc,
    const float* __restrict__ kp1, const float* __restrict__ w_kp1,
    const float* __restrict__ homo,
    unsigned short* __restrict__ d2t, unsigned short* __restrict__ q_bf,
    unsigned short* __restrict__ w_bf, float* __restrict__ pos,
    int* __restrict__ cid4, int* __restrict__ wcc16, int* __restrict__ wid4,
    unsigned int* __restrict__ marked, int* __restrict__ scnt,
    float* __restrict__ acc) {
    int blk = blockIdx.x;
    int tid = threadIdx.x;
    if (blk < 1024) {
        __shared__ float tile[32][129];
        int b = blk >> 9;
        int j0 = (blk & 511) * 32;
        int jj = tid & 31, cg = tid >> 5;
        const float* src = desc2 + (size_t)b * C_ * HW_;
#pragma unroll
        for (int cc = 0; cc < 16; ++cc) {
            int c = cg * 16 + cc;
            tile[jj][c] = src[(size_t)c * HW_ + j0 + jj];
        }
        __syncthreads();
        int row = tid >> 3, c8 = (tid & 7) * 16;
        unsigned int tmp[16];
#pragma unroll
        for (int k = 0; k < 16; ++k) tmp[k] = f2bf(tile[row][c8 + k]);
        uint4 o0, o1;
        o0.x = tmp[0] | (tmp[1] << 16);  o0.y = tmp[2] | (tmp[3] << 16);
        o0.z = tmp[4] | (tmp[5] << 16);  o0.w = tmp[6] | (tmp[7] << 16);
        o1.x = tmp[8] | (tmp[9] << 16);  o1.y = tmp[10] | (tmp[11] << 16);
        o1.z = tmp[12] | (tmp[13] << 16); o1.w = tmp[14] | (tmp[15] << 16);
        unsigned short* dst = d2t + ((size_t)(b << 14) + j0 + row) * C_ + c8;
        ((uint4*)dst)[0] = o0;
        ((uint4*)dst)[1] = o1;
    } else if (blk < 1152) {
        int idx = (blk - 1024) * 256 + tid;
        float4 v = *(const float4*)(kp1_desc + (size_t)idx * 4);
        uint2 u;
        u.x = f2bf(v.x) | (f2bf(v.y) << 16);
        u.y = f2bf(v.z) | (f2bf(v.w) << 16);
        *(uint2*)(q_bf + (size_t)idx * 4) = u;
    } else if (blk == 1152) {
        ((int4*)scnt)[tid] = make_int4(0, 0, 0, 0);
        if (tid < 64) acc[tid] = 0.0f;
    } else if (blk < 1157) {
        int t = (blk - 1153) * 256 + tid;
        if (t < B_ * N_)
            k1_body(t, kp1, w_kp1, homo, cid4, wcc16, wid4, marked);
    } else {
        int w = tid >> 6, l = tid & 63;
        int bn = (blk - 1157) * 4 + w;
        int b = bn / N_;
        float ky = w_kp1[2 * bn], kx = w_kp1[2 * bn + 1];
        float y = fminf(fmaxf(ky * 0.125f - 0.5f, 0.0f), (float)(H_ - 1));
        float x = fminf(fmaxf(kx * 0.125f - 0.5f, 0.0f), (float)(W_ - 1));
        int y0 = (int)floorf(y); if (y0 > H_ - 2) y0 = H_ - 2;
        int x0 = (int)floorf(x); if (x0 > W_ - 2) x0 = W_ - 2;
        float wy = y - (float)y0, wx = x - (float)x0;
        int i00 = y0 * W_ + x0;
        float w00 = (1.0f - wy) * (1.0f - wx), w01 = (1.0f - wy) * wx;
        float w10 = wy * (1.0f - wx),          w11 = wy * wx;
        const float* dB0 = desc2 + ((size_t)b * C_ + l) * HW_;
        const float* dB1 = desc2 + ((size_t)b * C_ + l + 64) * HW_;
        float v0 = dB0[i00] * w00 + dB0[i00 + 1] * w01
                 + dB0[i00 + W_] * w10 + dB0[i00 + W_ + 1] * w11;
        float v1 = dB1[i00] * w00 + dB1[i00 + 1] * w01
                 + dB1[i00 + W_] * w10 + dB1[i00 + W_ + 1] * w11;
        float s = v0 * v0 + v1 * v1;
        s += __shfl_xor(s, 1);  s += __shfl_xor(s, 2);  s += __shfl_xor(s, 4);
        s += __shfl_xor(s, 8);  s += __shfl_xor(s, 16); s += __shfl_xor(s, 32);
        float inv = 1.0f / (sqrtf(s) + 1e-8f);
        float vn0 = v0 * inv, vn1 = v1 * inv;
        w_bf[(size_t)bn * C_ + l]      = (unsigned short)f2bf(vn0);
        w_bf[(size_t)bn * C_ + 64 + l] = (unsigned short)f2bf(vn1);
        float qd0 = kp1_desc[(size_t)bn * C_ + l];
        float qd1 = kp1_desc[(size_t)bn * C_ + 64 + l];
        float d = qd0 * vn0 + qd1 * vn1;
        d += __shfl_xor(d, 1);  d += __shfl_xor(d, 2);  d += __shfl_xor(d, 4);
        d += __shfl_xor(d, 8);  d += __shfl_xor(d, 16); d += __shfl_xor(d, 32);
        if (l == 0) pos[bn] = 2.0f - 2.0f * d;
    }
}

// ---------------------------------------------------------------------------
// KB fused: [0,256) k3a rowmax pass; [256,384) k4a psim pass.
// ---------------------------------------------------------------------------
__global__ __launch_bounds__(512) void hqt_kb(
    const unsigned short* __restrict__ q_bf,
    const unsigned short* __restrict__ w_bf,
    const unsigned short* __restrict__ d2t,
    const int* __restrict__ cid4, const int* __restrict__ wid4,
    const int* __restrict__ wcc16,
    float* __restrict__ rowmax, float* __restrict__ psim) {
    int blk = blockIdx.x;
    int tid = threadIdx.x, w = tid >> 6, l = tid & 63;
    int l15 = l & 15, lg = l >> 4;
    if (blk < 256) {
        int b = blk >> 7;
        int rg = (blk >> 4) & 7;
        int cb = blk & 15;
        int rowbase = rg * 64;
        int colbase = cb * 1024 + w * 128;
        const unsigned short* qb = q_bf + (size_t)b * N_ * C_;
        const unsigned short* db = d2t + (size_t)b * HW_ * C_;
        short8 a[4][4];
#pragma unroll
        for (int rt = 0; rt < 4; ++rt)
#pragma unroll
            for (int ks = 0; ks < 4; ++ks)
                a[rt][ks] = *(const short8*)(qb + (size_t)(rowbase + rt * 16 + l15) * C_ + ks * 32 + lg * 8);
        f32x4 mx[4];
#pragma unroll
        for (int rt = 0; rt < 4; ++rt) mx[rt] = f32x4{-1e30f, -1e30f, -1e30f, -1e30f};
#pragma unroll
        for (int t = 0; t < 8; ++t) {
            const unsigned short* dp = db + (size_t)(colbase + t * 16 + l15) * C_ + lg * 8;
            short8 b0 = *(const short8*)(dp);
            short8 b1 = *(const short8*)(dp + 32);
            short8 b2 = *(const short8*)(dp + 64);
            short8 b3 = *(const short8*)(dp + 96);
#pragma unroll
            for (int rt = 0; rt < 4; ++rt) {
                f32x4 acc4 = {0.0f, 0.0f, 0.0f, 0.0f};
                acc4 = __builtin_amdgcn_mfma_f32_16x16x32_bf16(a[rt][0], b0, acc4, 0, 0, 0);
                acc4 = __builtin_amdgcn_mfma_f32_16x16x32_bf16(a[rt][1], b1, acc4, 0, 0, 0);
                acc4 = __builtin_amdgcn_mfma_f32_16x16x32_bf16(a[rt][2], b2, acc4, 0, 0, 0);
                acc4 = __builtin_amdgcn_mfma_f32_16x16x32_bf16(a[rt][3], b3, acc4, 0, 0, 0);
#pragma unroll
                for (int r = 0; r < 4; ++r) mx[rt][r] = fmaxf(mx[rt][r], acc4[r]);
            }
        }
#pragma unroll
        for (int rt = 0; rt < 4; ++rt)
#pragma unroll
            for (int r = 0; r < 4; ++r) {
                float v = mx[rt][r];
                v = fmaxf(v, __shfl_xor(v, 1));
                v = fmaxf(v, __shfl_xor(v, 2));
                v = fmaxf(v, __shfl_xor(v, 4));
                v = fmaxf(v, __shfl_xor(v, 8));
                mx[rt][r] = v;
            }
        if (l15 == 0) {
            int chunk = cb * 8 + w;
#pragma unroll
            for (int rt = 0; rt < 4; ++rt)
#pragma unroll
                for (int r = 0; r < 4; ++r) {
                    int rowg = b * N_ + rowbase + rt * 16 + lg * 4 + r;
                    rowmax[(size_t)rowg * 128 + chunk] = mx[rt][r];
                }
        }
    } else {
        int blk2 = blk - 256;
        int mat = blk2 >> 6;
        int b = (blk2 >> 5) & 1;
        int r0 = (blk2 & 31) * 16;
        const unsigned short* src = (mat ? w_bf : q_bf) + (size_t)b * N_ * C_;

        __shared__ int s_colids[N_][4];
        __shared__ int s_rowcc[16][16];
        {
            const int4* gsrc = (const int4*)((mat ? wid4 : cid4) + b * N_ * 4);
            ((int4*)s_colids)[tid] = gsrc[tid];
            if (tid < 256)
                ((int*)s_rowcc)[tid] = wcc16[(b * N_ + r0) * 16 + tid];
        }
        short8 a0 = *(const short8*)(src + (size_t)(r0 + l15) * C_ + lg * 8);
        short8 a1 = *(const short8*)(src + (size_t)(r0 + l15) * C_ + 32 + lg * 8);
        short8 a2 = *(const short8*)(src + (size_t)(r0 + l15) * C_ + 64 + lg * 8);
        short8 a3 = *(const short8*)(src + (size_t)(r0 + l15) * C_ + 96 + lg * 8);
        __syncthreads();

        int4 rowc[4];
        int rcc[4][16];
#pragma unroll
        for (int r = 0; r < 4; ++r) {
            rowc[r] = *(const int4*)(&s_colids[r0 + lg * 4 + r][0]);
            if (mat == 1) {
#pragma unroll
                for (int i = 0; i < 16; ++i) rcc[r][i] = s_rowcc[lg * 4 + r][i];
            }
        }

        float* prow = psim + ((size_t)(mat * B_ + b) * N_) * N_;
#pragma unroll
        for (int t = 0; t < 4; ++t) {
            int col0 = w * 64 + t * 16;
            const unsigned short* dp = src + (size_t)(col0 + l15) * C_ + lg * 8;
            short8 b0 = *(const short8*)(dp);
            short8 b1 = *(const short8*)(dp + 32);
            short8 b2 = *(const short8*)(dp + 64);
            short8 b3 = *(const short8*)(dp + 96);
            f32x4 acc4 = {0.0f, 0.0f, 0.0f, 0.0f};
            acc4 = __builtin_amdgcn_mfma_f32_16x16x32_bf16(a0, b0, acc4, 0, 0, 0);
            acc4 = __builtin_amdgcn_mfma_f32_16x16x32_bf16(a1, b1, acc4, 0, 0, 0);
            acc4 = __builtin_amdgcn_mfma_f32_16x16x32_bf16(a2, b2, acc4, 0, 0, 0);
            acc4 = __builtin_amdgcn_mfma_f32_16x16x32_bf16(a3, b3, acc4, 0, 0, 0);
            int mycol = col0 + l15;
            int4 cc = *(const int4*)(&s_colids[mycol][0]);
#pragma unroll
            for (int r = 0; r < 4; ++r) {
                int cnt = 0;
                if (mat == 0) {
#pragma unroll
                    for (int j = 0; j < 4; ++j) {
                        int u = (j == 0) ? rowc[r].x : (j == 1) ? rowc[r].y
                              : (j == 2) ? rowc[r].z : rowc[r].w;
                        cnt += (u == cc.x) + (u == cc.y) + (u == cc.z) + (u == cc.w);
                    }
                } else {
#pragma unroll
                    for (int i = 0; i < 16; ++i) {
                        int u = rcc[r][i];
                        cnt += (u == cc.x) + (u == cc.y) + (u == cc.z) + (u == cc.w);
                    }
                }
                float key = acc4[r] - 2.5f * (float)cnt;
                prow[(size_t)(r0 + lg * 4 + r) * N_ + mycol] = key;
            }
        }
    }
}

// ---------------------------------------------------------------------------
// K3b: broadcast rank-scan for t32.
// ---------------------------------------------------------------------------
__global__ __launch_bounds__(256) void hqt_k3b(
    const float* __restrict__ rowmax, float* __restrict__ t32) {
    int w = threadIdx.x >> 6, l = threadIdx.x & 63;
    int row = blockIdx.x * 4 + w;
    __shared__ float sm[4][128];
    const float* rm = rowmax + (size_t)row * 128;
    float c0 = rm[l];
    float c1 = rm[64 + l];
    sm[w][l] = c0;
    sm[w][64 + l] = c1;
    __syncthreads();
    int r0 = 0, r1 = 0;
    for (int j = 0; j < 128; j += 4) {
        float4 kk = *(const float4*)&sm[w][j];
#pragma unroll
        for (int e = 0; e < 4; ++e) {
            float key = (e == 0) ? kk.x : (e == 1) ? kk.y : (e == 2) ? kk.z : kk.w;
            int jj = j + e;
            r0 += (key > c0) || (key == c0 && jj < l);
            r1 += (key > c1) || (key == c1 && jj < 64 + l);
        }
    }
    if (r0 == 31) t32[row] = c0;
    if (r1 == 31) t32[row] = c1;
}

// ---------------------------------------------------------------------------
// KC: survivor pass (t32 from global).
// ---------------------------------------------------------------------------
__global__ __launch_bounds__(512) void hqt_kc(
    const unsigned short* __restrict__ q_bf,
    const unsigned short* __restrict__ d2t,
    const float* __restrict__ t32,
    int* __restrict__ scnt, float2* __restrict__ sbuf) {
    int blk = blockIdx.x;
    int b = blk >> 7;
    int rg = (blk >> 4) & 7;
    int cb = blk & 15;
    int tid = threadIdx.x, w = tid >> 6, l = tid & 63;
    int l15 = l & 15, lg = l >> 4;
    int rowbase = rg * 64;
    int colbase = cb * 1024 + w * 128;
    const unsigned short* qb = q_bf + (size_t)b * N_ * C_;
    const unsigned short* db = d2t + (size_t)b * HW_ * C_;
    short8 a[4][4];
#pragma unroll
    for (int rt = 0; rt < 4; ++rt)
#pragma unroll
        for (int ks = 0; ks < 4; ++ks)
            a[rt][ks] = *(const short8*)(qb + (size_t)(rowbase + rt * 16 + l15) * C_ + ks * 32 + lg * 8);
    float tl[4][4];
#pragma unroll
    for (int rt = 0; rt < 4; ++rt)
#pragma unroll
        for (int r = 0; r < 4; ++r)
            tl[rt][r] = t32[b * N_ + rowbase + rt * 16 + lg * 4 + r];
#pragma unroll
    for (int t = 0; t < 8; ++t) {
        const unsigned short* dp = db + (size_t)(colbase + t * 16 + l15) * C_ + lg * 8;
        short8 b0 = *(const short8*)(dp);
        short8 b1 = *(const short8*)(dp + 32);
        short8 b2 = *(const short8*)(dp + 64);
        short8 b3 = *(const short8*)(dp + 96);
#pragma unroll
        for (int rt = 0; rt < 4; ++rt) {
            f32x4 acc4 = {0.0f, 0.0f, 0.0f, 0.0f};
            acc4 = __builtin_amdgcn_mfma_f32_16x16x32_bf16(a[rt][0], b0, acc4, 0, 0, 0);
            acc4 = __builtin_amdgcn_mfma_f32_16x16x32_bf16(a[rt][1], b1, acc4, 0, 0, 0);
            acc4 = __builtin_amdgcn_mfma_f32_16x16x32_bf16(a[rt][2], b2, acc4, 0, 0, 0);
            acc4 = __builtin_amdgcn_mfma_f32_16x16x32_bf16(a[rt][3], b3, acc4, 0, 0, 0);
#pragma unroll
            for (int r = 0; r < 4; ++r) {
                float d = acc4[r];
                if (d >= tl[rt][r]) {
                    int rowg = b * N_ + rowbase + rt * 16 + lg * 4 + r;
                    int idx = atomicAdd(scnt + rowg, 1);
                    if (idx < SCAP_) {
                        float2 e;
                        e.x = d;
                        e.y = __int_as_float(colbase + t * 16 + l15);
                        sbuf[(size_t)rowg * SCAP_ + idx] = e;
                    }
                }
            }
        }
    }
}

// ---------------------------------------------------------------------------
// KD: [0,256) fos via rank-scan top-16 -> acc[0];
//     [256,512) sos via rank-scan top-8 -> acc[32]. No fence/ticket.
// ---------------------------------------------------------------------------
__global__ __launch_bounds__(256) void hqt_kd(
    const unsigned short* __restrict__ q_bf,
    const unsigned short* __restrict__ d2t,
    const unsigned int* __restrict__ marked,
    const int* __restrict__ scnt, const float2* __restrict__ sbuf,
    const float* __restrict__ pos, const float* __restrict__ psim,
    const int* __restrict__ cid4, const int* __restrict__ wid4,
    const int* __restrict__ wcc16, float* __restrict__ acc) {
    int blk = blockIdx.x;
    int w = threadIdx.x >> 6, l = threadIdx.x & 63;
    if (blk < 256) {
        // ================= fos: exact penalized top-16 via rank-scan ======
        __shared__ float keys[4][160];
        int row = blk * 4 + w;
        int b = row >> 9;
        int sc = scnt[row]; if (sc > SCAP_) sc = SCAP_;
        float k0 = -1e30f, k1 = -1e30f;
        int c0 = -1, c1 = -1;
        if (l < sc) {
            float2 e = sbuf[(size_t)row * SCAP_ + l];
            k0 = e.x; c0 = __float_as_int(e.y);
        }
        if (64 + l < sc) {
            float2 e = sbuf[(size_t)row * SCAP_ + 64 + l];
            k1 = e.x; c1 = __float_as_int(e.y);
        }
#pragma unroll
        for (int i = 0; i < 16; ++i) {
            unsigned int mv = marked[row * 16 + i];
            int id = (int)(mv & 0xFFFFu);
            if (c0 == id) k0 = -1e30f;
            if (c1 == id) k1 = -1e30f;
        }
        // marked keys (exact, 4 lanes per marked slot)
        float k2c = -1e30f;
        int mi = l >> 2;
        {
            int cq = l & 3;
            unsigned int mv = marked[row * 16 + mi];
            bool valid = (mv != 0xFFFFFFFFu);
            int col = valid ? (int)(mv & 0xFFFFu) : 0;
            int cnt = (int)(mv >> 16);
            const unsigned short* qp = q_bf + (size_t)row * C_ + cq * 32;
            const unsigned short* dp = d2t + ((size_t)b * HW_ + col) * C_ + cq * 32;
            float dot = 0.0f;
#pragma unroll
            for (int u = 0; u < 4; ++u) {
                short8 qv = *(const short8*)(qp + u * 8);
                short8 dv = *(const short8*)(dp + u * 8);
#pragma unroll
                for (int e = 0; e < 8; ++e)
                    dot = fmaf(bf2f((unsigned short)qv[e]), bf2f((unsigned short)dv[e]), dot);
            }
            dot += __shfl_xor(dot, 1);
            dot += __shfl_xor(dot, 2);
            k2c = valid ? (dot - 2.5f * (float)cnt) : -1e30f;
            // stage keys
            keys[w][l] = k0;
            keys[w][64 + l] = k1;
            if (cq == 0) keys[w][128 + mi] = k2c;
            if (l < 16) keys[w][144 + l] = -1e30f;   // pad
        }
        __syncthreads();
        // rank-scan: candidates (k0@l), (k1@64+l), (k2c@128+l for l<16)
        float cC = (l < 16) ? keys[w][128 + l] : -1e30f;
        int idxC = 128 + l;
        int r0 = 0, r1 = 0, r2 = 0;
        for (int j = 0; j < 144; j += 4) {
            float4 kk = *(const float4*)&keys[w][j];
#pragma unroll
            for (int e = 0; e < 4; ++e) {
                float key = (e == 0) ? kk.x : (e == 1) ? kk.y : (e == 2) ? kk.z : kk.w;
                int jj = j + e;
                r0 += (key > k0) || (key == k0 && jj < l);
                r1 += (key > k1) || (key == k1 && jj < 64 + l);
                r2 += (key > cC) || (key == cC && jj < idxC);
            }
        }
        float pos_r = pos[row];
        float sum = 0.0f;
        if (r0 < 16) { float h = fmaxf(pos_r + 2.0f * k0 - 1.0f, 0.0f); sum += h * h; }
        if (r1 < 16) { float h = fmaxf(pos_r + 2.0f * k1 - 1.0f, 0.0f); sum += h * h; }
        if (r2 < 16) { float h = fmaxf(pos_r + 2.0f * cC - 1.0f, 0.0f); sum += h * h; }
        sum += __shfl_xor(sum, 1);  sum += __shfl_xor(sum, 2);
        sum += __shfl_xor(sum, 4);  sum += __shfl_xor(sum, 8);
        sum += __shfl_xor(sum, 16); sum += __shfl_xor(sum, 32);
        if (l == 0) atomicAdd(acc + 0, sum);
    } else {
        // ================= sos: rank-scan top-8 per (row, mat) ============
        __shared__ float cand[4][128];
        __shared__ float sval[4][64];
        __shared__ int   scol[4][64];
        __shared__ int   cnt_l[4];
        __shared__ float tpp[4];
        __shared__ float sel[4][2][8];
        int rowg = (blk - 256) * 4 + w;
        int b = rowg >> 9;
        int row = rowg & 511;
#pragma unroll 1
        for (int mat = 0; mat < 2; ++mat) {
            const float* pr = psim + ((size_t)(mat * B_ + b) * N_ + row) * N_;
            float4 u0 = ((const float4*)pr)[l * 2];
            float4 u1 = ((const float4*)pr)[l * 2 + 1];
            float k[8] = {u0.x, u0.y, u0.z, u0.w, u1.x, u1.y, u1.z, u1.w};
            // per-lane top-2 (values only)
            float m1 = -1e30f, m2 = -1e30f;
#pragma unroll
            for (int i = 0; i < 8; ++i) {
                float v = k[i];
                bool g1 = v > m1;
                m2 = g1 ? m1 : fmaxf(m2, v);
                m1 = g1 ? v : m1;
            }
            if (l == 0) cnt_l[w] = 0;
            cand[w][l] = m1;
            cand[w][64 + l] = m2;
            __syncthreads();
            // t8' = 8th largest of the 128-set (strict by value, then slot)
            int rA = 0, rB = 0;
            for (int j = 0; j < 128; j += 4) {
                float4 cc = *(const float4*)&cand[w][j];
#pragma unroll
                for (int e = 0; e < 4; ++e) {
                    float cv = (e == 0) ? cc.x : (e == 1) ? cc.y : (e == 2) ? cc.z : cc.w;
                    int jj = j + e;
                    rA += (cv > m1) || (cv == m1 && jj < l);
                    rB += (cv > m2) || (cv == m2 && jj < 64 + l);
                }
            }
            if (rA == 7) tpp[w] = m1;
            if (rB == 7) tpp[w] = m2;
            __syncthreads();
            float t8 = tpp[w];
            // survivors (v >= t8 by value) -> LDS via atomic ticket
#pragma unroll
            for (int i = 0; i < 8; ++i) {
                if (k[i] >= t8) {
                    int s = atomicAdd(&cnt_l[w], 1);
                    if (s < 64) { sval[w][s] = k[i]; scol[w][s] = l * 8 + i; }
                }
            }
            __syncthreads();
            int cnt = cnt_l[w]; if (cnt > 64) cnt = 64;
            // rank survivors: (value desc, col asc) == lax.top_k order
            float sv = (l < cnt) ? sval[w][l] : -1e30f;
            int   scm = (l < cnt) ? scol[w][l] : INT_MAX;
            int r = 0;
            for (int j = 0; j < cnt; ++j) {
                float vj = sval[w][j];
                int cj = scol[w][j];
                r += (vj > sv) || (vj == sv && cj < scm);
            }
            if (l < cnt && r < 8) {
                // reconstruct clean dot: key + 2.5 * exact mask count
                int cntm = 0;
                if (mat == 0) {
                    const int4* cb4 = (const int4*)(cid4 + b * N_ * 4);
                    int4 rc = cb4[row];
                    int4 mc = cb4[scm];
#pragma unroll
                    for (int j = 0; j < 4; ++j) {
                        int u = (j == 0) ? rc.x : (j == 1) ? rc.y : (j == 2) ? rc.z : rc.w;
                        cntm += (u == mc.x) + (u == mc.y) + (u == mc.z) + (u == mc.w);
                    }
                } else {
                    const int4* wb4 = (const int4*)(wid4 + b * N_ * 4);
                    int4 mw = wb4[scm];
                    const int4* rcc = (const int4*)(wcc16 + (b * N_ + row) * 16);
#pragma unroll
                    for (int uq = 0; uq < 4; ++uq) {
                        int4 rr = rcc[uq];
                        cntm += (rr.x == mw.x) + (rr.x == mw.y) + (rr.x == mw.z) + (rr.x == mw.w);
                        cntm += (rr.y == mw.x) + (rr.y == mw.y) + (rr.y == mw.z) + (rr.y == mw.w);
                        cntm += (rr.z == mw.x) + (rr.z == mw.y) + (rr.z == mw.z) + (rr.z == mw.w);
                        cntm += (rr.w == mw.x) + (rr.w == mw.y) + (rr.w == mw.z) + (rr.w == mw.w);
                    }
                }
                sel[w][mat][r] = sv + 2.5f * (float)cntm;
            }
            __syncthreads();
        }
        if (l < 8) {
            float t2 = 2.0f * (sel[w][1][l] - sel[w][0][l]);
            float sq = t2 * t2;
            sq += __shfl_xor(sq, 1);
            sq += __shfl_xor(sq, 2);
            sq += __shfl_xor(sq, 4);
            if (l == 0) atomicAdd(acc + 32, sqrtf(sq));
        }
    }
}

// ---------------------------------------------------------------------------
// K5 (new path): finalize from acc[0] (fos) and acc[32] (sos).
// ---------------------------------------------------------------------------
__global__ void hqt_k5_final2(const float* __restrict__ acc, float* __restrict__ out) {
    if (threadIdx.x == 0 && blockIdx.x == 0) {
        out[0] = acc[0] * (1.0f / (float)(B_ * N_ * NUM_NEG_))
               + acc[32] * (1.0f / (float)(B_ * N_));
    }
}

// ======================= fallback (round-1) kernels ========================
__global__ void hqt_k1_cells(const float* __restrict__ kp1,
                             const float* __restrict__ w_kp1,
                             const float* __restrict__ homo,
                             int* __restrict__ cid4,
                             int* __restrict__ wcc16,
                             int* __restrict__ wid4) {
    int t = blockIdx.x * blockDim.x + threadIdx.x;
    if (t >= B_ * N_) return;
    int b = t / N_;
    float ky = kp1[2 * t], kx = kp1[2 * t + 1];
    int ids[4];
    nearest4(ky, kx, ids);
    const float* Hb = homo + 9 * b;
    float h00 = Hb[0], h01 = Hb[1], h02 = Hb[2];
    float h10 = Hb[3], h11 = Hb[4], h12 = Hb[5];
    float h20 = Hb[6], h21 = Hb[7], h22 = Hb[8];
#pragma unroll
    for (int i = 0; i < 4; ++i) {
        int id = ids[i];
        cid4[4 * t + i] = id;
        float cy = 8.0f * (id >> 7) + 4.0f;
        float cx = 8.0f * (id & 127) + 4.0f;
        float X = cx, Y = cy;
        float wz = h20 * X + h21 * Y + h22;
        float inv = 1.0f / (wz + 1e-8f);
        float wy = (h10 * X + h11 * Y + h12) * inv;
        float wx = (h00 * X + h01 * Y + h02) * inv;
        int wids[4];
        nearest4(wy, wx, wids);
#pragma unroll
        for (int j = 0; j < 4; ++j) wcc16[16 * t + 4 * i + j] = wids[j];
    }
    float zy = w_kp1[2 * t], zx = w_kp1[2 * t + 1];
    int wi4[4];
    nearest4(zy, zx, wi4);
#pragma unroll
    for (int j = 0; j < 4; ++j) wid4[4 * t + j] = wi4[j];
}

__global__ __launch_bounds__(128) void hqt_k2_sample_f32(
    const float* __restrict__ w_kp1, const float* __restrict__ desc2,
    const float* __restrict__ kp1_desc, float* __restrict__ w_desc,
    float* __restrict__ pos) {
    int bn = blockIdx.x;
    int b = bn / N_;
    int c = threadIdx.x;
    float ky = w_kp1[2 * bn], kx = w_kp1[2 * bn + 1];
    float y = fminf(fmaxf(ky * 0.125f - 0.5f, 0.0f), (float)(H_ - 1));
    float x = fminf(fmaxf(kx * 0.125f - 0.5f, 0.0f), (float)(W_ - 1));
    int y0 = (int)floorf(y); if (y0 > H_ - 2) y0 = H_ - 2;
    int x0 = (int)floorf(x); if (x0 > W_ - 2) x0 = W_ - 2;
    float wy = y - (float)y0, wx = x - (float)x0;
    const float* dB = desc2 + ((size_t)b * C_ + c) * HW_;
    int i00 = y0 * W_ + x0;
    float v = dB[i00]          * (1.0f - wy) * (1.0f - wx)
            + dB[i00 + 1]      * (1.0f - wy) * wx
            + dB[i00 + W_]     * wy * (1.0f - wx)
            + dB[i00 + W_ + 1] * wy * wx;
    __shared__ float red[128];
    red[c] = v * v;
    __syncthreads();
    for (int s = 64; s > 0; s >>= 1) {
        if (c < s) red[c] += red[c + s];
        __syncthreads();
    }
    float nrm = sqrtf(red[0]);
    __syncthreads();
    float vn = v / (nrm + 1e-8f);
    w_desc[(size_t)bn * C_ + c] = vn;
    float qd = kp1_desc[(size_t)bn * C_ + c];
    red[c] = qd * vn;
    __syncthreads();
    for (int s = 64; s > 0; s >>= 1) {
        if (c < s) red[c] += red[c + s];
        __syncthreads();
    }
    if (c == 0) pos[bn] = 2.0f - 2.0f * red[0];
}

__device__ inline void insert8_vi(float (&av)[8], int (&ai)[8], float v, int id) {
    bool le = (v < av[7]) || (v == av[7] && id < ai[7]);
    if (!le) return;
#pragma unroll
    for (int k = 0; k < 8; ++k) {
        float ov = av[k]; int oi = ai[k];
        bool sm = (v < ov) || (v == ov && id < oi);
        av[k] = sm ? v : ov;  ai[k] = sm ? id : oi;
        v = sm ? ov : v;      id = sm ? oi : id;
    }
}

__device__ inline void bitonic8_pairs(float (&av)[8], int (&ai)[8]) {
#pragma unroll
    for (int dd = 0; dd < 3; ++dd) {
        const int d = 4 >> dd;
#pragma unroll
        for (int i = 0; i < 8; ++i) {
            if ((i & d) == 0) {
                bool sw = (av[i + d] < av[i]) ||
                          (av[i + d] == av[i] && ai[i + d] < ai[i]);
                float tv = av[i]; int ti = ai[i];
                av[i]     = sw ? av[i + d] : av[i];
                ai[i]     = sw ? ai[i + d] : ai[i];
                av[i + d] = sw ? tv : av[i + d];
                ai[i + d] = sw ? ti : ai[i + d];
            }
        }
    }
}

__device__ inline void bitonic16_asc(float (&a)[16]) {
#pragma unroll
    for (int dd = 0; dd < 4; ++dd) {
        const int d = 8 >> dd;
#pragma unroll
        for (int i = 0; i < 16; ++i) {
            if ((i & d) == 0) {
                float lo = fminf(a[i], a[i + d]);
                float hi = fmaxf(a[i], a[i + d]);
                a[i] = lo; a[i + d] = hi;
            }
        }
    }
}

#define T3 512
#define R3 4
__global__ __launch_bounds__(T3) void hqt_k3_dsim(
    const float* __restrict__ desc2, const float* __restrict__ kp1_desc,
    const int* __restrict__ wcc16, const float* __restrict__ pos,
    float* __restrict__ acc) {
    const int nb = N_ / R3;
    int b = blockIdx.x / nb;
    int n0 = (blockIdx.x % nb) * R3;
    int tid = threadIdx.x;
    __shared__ float qT[C_][R3];
    __shared__ int ids_s[R3][16];
    {
        int r = tid & 3, c = tid >> 2;
        qT[c][r] = kp1_desc[(size_t)(b * N_ + n0 + r) * C_ + c];
    }
    if (tid < R3 * 16)
        ids_s[tid >> 4][tid & 15] = wcc16[(b * N_ + n0) * 16 + tid];
    __syncthreads();

    float top[R3][16];
#pragma unroll
    for (int r = 0; r < R3; ++r)
#pragma unroll
        for (int k = 0; k < 16; ++k) top[r][k] = 1e30f;

    const float* d2b = desc2 + (size_t)b * C_ * HW_;
#pragma unroll 1
    for (int g = 0; g < HW_ / (T3 * 4); ++g) {
        int j0 = (g * T3 + tid) * 4;
        float4 A0 = {0, 0, 0, 0}, A1 = {0, 0, 0, 0}, A2 = {0, 0, 0, 0}, A3 = {0, 0, 0, 0};
        for (int c = 0; c < C_; ++c) {
            float4 d = *reinterpret_cast<const float4*>(d2b + (size_t)c * HW_ + j0);
            float4 qv = *reinterpret_cast<const float4*>(&qT[c][0]);
            A0.x = fmaf(qv.x, d.x, A0.x); A0.y = fmaf(qv.x, d.y, A0.y);
            A0.z = fmaf(qv.x, d.z, A0.z); A0.w = fmaf(qv.x, d.w, A0.w);
            A1.x = fmaf(qv.y, d.x, A1.x); A1.y = fmaf(qv.y, d.y, A1.y);
            A1.z = fmaf(qv.y, d.z, A1.z); A1.w = fmaf(qv.y, d.w, A1.w);
            A2.x = fmaf(qv.z, d.x, A2.x); A2.y = fmaf(qv.z, d.y, A2.y);
            A2.z = fmaf(qv.z, d.z, A2.z); A2.w = fmaf(qv.z, d.w, A2.w);
            A3.x = fmaf(qv.w, d.x, A3.x); A3.y = fmaf(qv.w, d.y, A3.y);
            A3.z = fmaf(qv.w, d.z, A3.z); A3.w = fmaf(qv.w, d.w, A3.w);
        }
#pragma unroll
        for (int r = 0; r < R3; ++r) {
            float dots[4];
            dots[0] = (r == 0) ? A0.x : (r == 1) ? A1.x : (r == 2) ? A2.x : A3.x;
            dots[1] = (r == 0) ? A0.y : (r == 1) ? A1.y : (r == 2) ? A2.y : A3.y;
            dots[2] = (r == 0) ? A0.z : (r == 1) ? A1.z : (r == 2) ? A2.z : A3.z;
            dots[3] = (r == 0) ? A0.w : (r == 1) ? A1.w : (r == 2) ? A2.w : A3.w;
#pragma unroll
        for (int cc = 0; cc < 4; ++cc) {
                int j = j0 + cc;
                int cnt = 0;
#pragma unroll
                for (int i = 0; i < 16; ++i) cnt += (ids_s[r][i] == j) ? 1 : 0;
                float v = 2.0f - 2.0f * dots[cc] + 5.0f * (float)cnt;
                if (v < top[r][15]) {
#pragma unroll
                    for (int k = 0; k < 16; ++k) {
                        float o = top[r][k];
                        bool sm = v < o;
                        top[r][k] = sm ? v : o;
                        v = sm ? o : v;
                    }
                }
            }
        }
    }

    __shared__ float mv[T3][17];
#pragma unroll
    for (int r = 0; r < R3; ++r) {
        float a[16];
#pragma unroll
        for (int k = 0; k < 16; ++k) { a[k] = top[r][k]; mv[tid][k] = a[k]; }
        __syncthreads();
        for (int step = T3 / 2; step >= 1; step >>= 1) {
            if (tid < step) {
#pragma unroll
                for (int i = 0; i < 16; ++i)
                    a[i] = fminf(a[i], mv[tid + step][15 - i]);
                bitonic16_asc(a);
#pragma unroll
                for (int i = 0; i < 16; ++i) mv[tid][i] = a[i];
            }
            __syncthreads();
        }
        if (tid == 0) {
            float p = pos[b * N_ + n0 + r];
            float s = 0.0f;
#pragma unroll
            for (int k = 0; k < 16; ++k) {
                float xv = p - a[k] + 1.0f;
                xv = fmaxf(xv, 0.0f);
                s += xv * xv;
            }
            atomicAdd(acc + 0, s);
        }
        __syncthreads();
    }
}

__global__ __launch_bounds__(64) void hqt_k4_sos(
    const float* __restrict__ kp1_desc, const float* __restrict__ w_desc,
    const int* __restrict__ cid4, const int* __restrict__ wcc16,
    const int* __restrict__ wid4, float* __restrict__ acc) {
    int bn = blockIdx.x;
    int b = bn / N_;
    int lane = threadIdx.x;
    __shared__ float qk[C_], qw[C_];
    for (int c = lane; c < C_; c += 64) {
        qk[c] = kp1_desc[(size_t)bn * C_ + c];
        qw[c] = w_desc[(size_t)bn * C_ + c];
    }
    __syncthreads();
    int nk[4];
#pragma unroll
    for (int i = 0; i < 4; ++i) nk[i] = cid4[4 * bn + i];
    int nw[16];
#pragma unroll
    for (int i = 0; i < 16; ++i) nw[i] = wcc16[16 * bn + i];

    float kv[8], wv[8]; int ki[8], wi[8];
#pragma unroll
    for (int k = 0; k < 8; ++k) {
        kv[k] = 1e30f; wv[k] = 1e30f; ki[k] = INT_MAX; wi[k] = INT_MAX;
    }
    const float* kb = kp1_desc + (size_t)b * N_ * C_;
    const float* wb = w_desc + (size_t)b * N_ * C_;
    for (int tt = 0; tt < 8; ++tt) {
        int m = lane * 8 + tt;
        const float* rk = kb + (size_t)m * C_;
        const float* rw = wb + (size_t)m * C_;
        float dk = 0.0f, dw = 0.0f;
        for (int c = 0; c < C_; c += 4) {
            float4 xk = *(const float4*)(rk + c);
            float4 xw = *(const float4*)(rw + c);
            dk += qk[c] * xk.x + qk[c + 1] * xk.y + qk[c + 2] * xk.z + qk[c + 3] * xk.w;
            dw += qw[c] * xw.x + qw[c + 1] * xw.y + qw[c + 2] * xw.z + qw[c + 3] * xw.w;
        }
        int4 mc = *(const int4*)(cid4 + 4 * (b * N_ + m));
        int ck = 0;
#pragma unroll
        for (int i = 0; i < 4; ++i) {
            int u = nk[i];
            ck += (u == mc.x) + (u == mc.y) + (u == mc.z) + (u == mc.w);
        }
        int4 mw = *(const int4*)(wid4 + 4 * (b * N_ + m));
        int cw = 0;
#pragma unroll
        for (int i = 0; i < 16; ++i) {
            int u = nw[i];
            cw += (u == mw.x) + (u == mw.y) + (u == mw.z) + (u == mw.w);
        }
        float vk = 2.0f - 2.0f * dk + 5.0f * (float)ck;
        float vw2 = 2.0f - 2.0f * dw + 5.0f * (float)cw;
        insert8_vi(kv, ki, vk, m);
        insert8_vi(wv, wi, vw2, m);
    }

    __shared__ float mvs[64][9];
    __shared__ int mis[64][9];
    __shared__ int fk[8], fw[8];

#pragma unroll
    for (int i = 0; i < 8; ++i) { mvs[lane][i] = kv[i]; mis[lane][i] = ki[i]; }
    __syncthreads();
    for (int step = 32; step >= 1; step >>= 1) {
        if (lane < step) {
            float bv[8]; int bix[8];
#pragma unroll
            for (int i = 0; i < 8; ++i) {
                bv[i] = mvs[lane + step][7 - i];
                bix[i] = mis[lane + step][7 - i];
            }
#pragma unroll
            for (int i = 0; i < 8; ++i) {
                bool ta = (kv[i] < bv[i]) || (kv[i] == bv[i] && ki[i] < bix[i]);
                kv[i] = ta ? kv[i] : bv[i];
                ki[i] = ta ? ki[i] : bix[i];
            }
            bitonic8_pairs(kv, ki);
#pragma unroll
            for (int i = 0; i < 8; ++i) { mvs[lane][i] = kv[i]; mis[lane][i] = ki[i]; }
        }
        __syncthreads();
    }
    if (lane < 8) fk[lane] = mis[0][lane];
    __syncthreads();

#pragma unroll
    for (int i = 0; i < 8; ++i) { mvs[lane][i] = wv[i]; mis[lane][i] = wi[i]; }
    __syncthreads();
    for (int step = 32; step >= 1; step >>= 1) {
        if (lane < step) {
            float bv[8]; int bix[8];
#pragma unroll
            for (int i = 0; i < 8; ++i) {
                bv[i] = mvs[lane + step][7 - i];
                bix[i] = mis[lane + step][7 - i];
            }
#pragma unroll
            for (int i = 0; i < 8; ++i) {
                bool ta = (wv[i] < bv[i]) || (wv[i] == bv[i] && wi[i] < bix[i]);
                wv[i] = ta ? wv[i] : bv[i];
                wi[i] = ta ? wi[i] : bix[i];
            }
            bitonic8_pairs(wv, wi);
#pragma unroll
            for (int i = 0; i < 8; ++i) { mvs[lane][i] = wv[i]; mis[lane][i] = wi[i]; }
        }
        __syncthreads();
    }
    if (lane < 8) fw[lane] = mis[0][lane];
    __syncthreads();

    int s = lane >> 3, p = lane & 7;
    const float* rk = kb + (size_t)fk[s] * C_;
    const float* rw = wb + (size_t)fw[s] * C_;
    float dk = 0.0f, dw = 0.0f;
    for (int c = p; c < C_; c += 8) {
        dk += qk[c] * rk[c];
        dw += qw[c] * rw[c];
    }
    dk += __shfl_xor(dk, 1); dk += __shfl_xor(dk, 2); dk += __shfl_xor(dk, 4);
    dw += __shfl_xor(dw, 1); dw += __shfl_xor(dw, 2); dw += __shfl_xor(dw, 4);
    __shared__ float tsq[8];
    if (p == 0) {
        float t2 = 2.0f * (dw - dk);
        tsq[s] = t2 * t2;
    }
    __syncthreads();
    if (lane == 0) {
        float s8 = 0.0f;
#pragma unroll
        for (int i = 0; i < 8; ++i) s8 += tsq[i];
        atomicAdd(acc + 1, sqrtf(s8));
    }
}

__global__ void hqt_k5_final(const float* __restrict__ acc, float* __restrict__ out) {
    if (threadIdx.x == 0 && blockIdx.x == 0) {
        out[0] = acc[0] * (1.0f / (float)(B_ * N_ * NUM_NEG_))
               + acc[1] * (1.0f / (float)(B_ * N_));
    }
}

// ===========================================================================
extern "C" void kernel_launch(void* const* d_in, const int* in_sizes, int n_in,
                              void* d_out, int out_size, void* d_ws, size_t ws_size,
                              hipStream_t stream) {
    const float* kp1      = (const float*)d_in[0];
    const float* w_kp1    = (const float*)d_in[1];
    const float* kp1_desc = (const float*)d_in[2];
    const float* desc2    = (const float*)d_in[3];
    const float* homo     = (const float*)d_in[4];
    float* out = (float*)d_out;

    char* p = (char*)d_ws;
    auto alloc = [&](size_t bytes) {
        char* r = p;
        p += (bytes + 255) & ~(size_t)255;
        return r;
    };
    float*          pos    = (float*)alloc((size_t)B_ * N_ * 4);
    int*            cid4   = (int*)alloc((size_t)B_ * N_ * 4 * 4);
    int*            wid4   = (int*)alloc((size_t)B_ * N_ * 4 * 4);
    int*            wcc16  = (int*)alloc((size_t)B_ * N_ * 16 * 4);
    unsigned int*   marked = (unsigned int*)alloc((size_t)B_ * N_ * 16 * 4);
    float*          acc    = (float*)alloc(256);
    unsigned short* q_bf   = (unsigned short*)alloc((size_t)B_ * N_ * C_ * 2);
    unsigned short* w_bf   = (unsigned short*)alloc((size_t)B_ * N_ * C_ * 2);
    unsigned short* d2t    = (unsigned short*)alloc((size_t)B_ * HW_ * C_ * 2);
    float*          psim   = (float*)alloc((size_t)2 * B_ * N_ * N_ * 4);
    float*          rowmax = (float*)alloc((size_t)B_ * N_ * 128 * 4);
    float*          t32    = (float*)alloc((size_t)B_ * N_ * 4);
    int*            scnt   = (int*)alloc((size_t)B_ * N_ * 4);
    float2*         sbuf   = (float2*)alloc((size_t)B_ * N_ * SCAP_ * 8);
    size_t need = (size_t)(p - (char*)d_ws);

    if (ws_size >= need) {
        hqt_ka<<<1413, 256, 0, stream>>>(desc2, kp1_desc, kp1, w_kp1, homo,
                                         d2t, q_bf, w_bf, pos, cid4, wcc16,
                                         wid4, marked, scnt, acc);
        hqt_kb<<<384, 512, 0, stream>>>(q_bf, w_bf, d2t, cid4, wid4, wcc16,
                                        rowmax, psim);
        hqt_k3b<<<256, 256, 0, stream>>>(rowmax, t32);
        hqt_kc<<<256, 512, 0, stream>>>(q_bf, d2t, t32, scnt, sbuf);
        hqt_kd<<<512, 256, 0, stream>>>(q_bf, d2t, marked, scnt, sbuf, pos,
                                        psim, cid4, wid4, wcc16, acc);
        hqt_k5_final2<<<1, 1, 0, stream>>>(acc, out);
    } else {
        // fallback: round-1 layout and path
        float* w_desc0 = (float*)d_ws;
        float* pos0    = w_desc0 + (size_t)B_ * N_ * C_;
        int*   cid40   = (int*)(pos0 + B_ * N_);
        int*   wid40   = cid40 + B_ * N_ * 4;
        int*   wcc160  = wid40 + B_ * N_ * 4;
        float* acc0    = (float*)(wcc160 + B_ * N_ * 16);
        hipMemsetAsync(acc0, 0, 2 * sizeof(float), stream);
        hqt_k1_cells<<<(B_ * N_ + 255) / 256, 256, 0, stream>>>(
            kp1, w_kp1, homo, cid40, wcc160, wid40);
        hqt_k2_sample_f32<<<B_ * N_, 128, 0, stream>>>(w_kp1, desc2, kp1_desc,
                                                       w_desc0, pos0);
        hqt_k3_dsim<<<B_ * (N_ / R3), T3, 0, stream>>>(desc2, kp1_desc, wcc160,
                                                       pos0, acc0);
        hqt_k4_sos<<<B_ * N_, 64, 0, stream>>>(kp1_desc, w_desc0, cid40,
                                               wcc160, wid40, acc0);
        hqt_k5_final<<<1, 1, 0, stream>>>(acc0, out);
    }
}